// Round 6
// baseline (584.029 us; speedup 1.0000x reference)
//
#include <hip/hip_runtime.h>
#include <math.h>

// Problem constants
#define BBATCH 8
#define CC 96
#define HH 224
#define NHW 32            // 224/7 windows per side
#define NWIN 1024
#define TOPK 256
#define PERK 24
#define DST 16
#define DTR 6
#define LL 12544          // 256*49
#define LC 98             // chunk length per block (2 sub-chunks = 2 scan windows)
#define LCP 52            // padded sub-chunk row length (49 used + 3 zero pad)
#define NG 13             // float4 groups per row
#define TCH 128           // chunks per (b,k): 128*98 = 12544
#define NBK 32            // B*4 directions

// workspace offsets (floats) — total 13,600,000 floats = 54.4 MB
#define OFF_POOL 0
#define OFF_LOG  786432
#define OFF_PROB 794624
#define OFF_RW   802816
#define OFF_RANK 804864
#define OFF_SEL  813056
#define OFF_WEFF 815104
#define OFF_CP   820480      // 1,572,864 floats; ALSO reused as hin (read-before-write in k_carry)
#define OFF_CS   2393344     // 1,572,864 floats
#define OFF_YWS  3966208     // 9,633,792 floats: y_ws[bk][l][d], d innermost

// DPP row_ror:N add — 16-lane full-sum reduction on the VALU pipe (not DS)
#define ROR_ADD(v, CTRL) \
    v += __int_as_float(__builtin_amdgcn_update_dpp(0, __float_as_int(v), CTRL, 0xf, 0xf, true))

// -------- K0: fold dt_proj into x_proj: Wcomb[k][56][24] --------
__global__ void k_weff(const float* __restrict__ xpw, const float* __restrict__ dtw,
                       float* __restrict__ wcomb) {
    int i = blockIdx.x * blockDim.x + threadIdx.x;
    if (i >= 4 * 56 * PERK) return;
    int k = i / (56 * PERK), rem = i - k * (56 * PERK);
    int row = rem / PERK, c = rem - row * PERK;
    float v;
    if (row < PERK) {
        v = 0.f;
        #pragma unroll
        for (int r = 0; r < DTR; ++r)
            v += dtw[(k * PERK + row) * DTR + r] * xpw[(k * 38 + r) * PERK + c];
    } else {
        v = xpw[(k * 38 + (row - PERK + DTR)) * PERK + c];
    }
    wcomb[i] = v;
}

// -------- K1: window pooling: pooledT[b][c][w] --------
__global__ void k_pool(const float* __restrict__ x, float* __restrict__ pooled) {
    int bc = blockIdx.x;                 // b*96+c
    const float* xp = x + (size_t)bc * HH * HH;
    float* pp = pooled + (size_t)bc * NWIN;
    for (int w = threadIdx.x; w < NWIN; w += blockDim.x) {
        int wr = w >> 5, wc = w & 31;
        const float* base = xp + (wr * 7) * HH + wc * 7;
        float s = 0.f;
        #pragma unroll
        for (int i = 0; i < 7; ++i) {
            #pragma unroll
            for (int j = 0; j < 7; ++j) s += base[i * HH + j];
        }
        pp[w] = s * (1.0f / 49.0f);
    }
}

// -------- K2: router MLP -> logits --------
__global__ void k_router(const float* __restrict__ pooled,
                         const float* __restrict__ w1, const float* __restrict__ b1,
                         const float* __restrict__ w2, const float* __restrict__ b2,
                         float* __restrict__ logits) {
    __shared__ float sw1[PERK * CC];
    __shared__ float sb1[PERK];
    __shared__ float sw2[PERK];
    for (int i = threadIdx.x; i < PERK * CC; i += blockDim.x) sw1[i] = w1[i];
    if (threadIdx.x < PERK) { sb1[threadIdx.x] = b1[threadIdx.x]; sw2[threadIdx.x] = w2[threadIdx.x]; }
    __syncthreads();
    int gid = blockIdx.x * blockDim.x + threadIdx.x;   // 8192 threads
    int b = gid >> 10, w = gid & 1023;
    float hid[PERK];
    #pragma unroll
    for (int j = 0; j < PERK; ++j) hid[j] = sb1[j];
    const float* pp = pooled + (size_t)b * CC * NWIN + w;
    for (int c = 0; c < CC; ++c) {
        float pv = pp[(size_t)c * NWIN];
        #pragma unroll
        for (int j = 0; j < PERK; ++j) hid[j] += pv * sw1[j * CC + c];
    }
    float lg = b2[0];
    #pragma unroll
    for (int j = 0; j < PERK; ++j) {
        float hv = hid[j];
        float g = 0.5f * hv * (1.0f + erff(hv * 0.7071067811865476f));
        lg += g * sw2[j];
    }
    logits[gid] = lg;
}

// -------- K3a: softmax over 1024 windows --------
__global__ void k_soft(const float* __restrict__ logits, float* __restrict__ probs) {
    __shared__ float red[NWIN];
    int b = blockIdx.x, t = threadIdx.x;
    float lg = logits[b * NWIN + t];
    red[t] = lg; __syncthreads();
    for (int o = 512; o > 0; o >>= 1) { if (t < o) red[t] = fmaxf(red[t], red[t + o]); __syncthreads(); }
    float mx = red[0]; __syncthreads();
    float e = expf(lg - mx);
    red[t] = e; __syncthreads();
    for (int o = 512; o > 0; o >>= 1) { if (t < o) red[t] += red[t + o]; __syncthreads(); }
    probs[b * NWIN + t] = e / red[0];
}

// -------- K3b: stable descending rank (distributed over 128 blocks) --------
__global__ __launch_bounds__(64) void k_rank2(const float* __restrict__ probs,
        float* __restrict__ rw, int* __restrict__ rank, int* __restrict__ sel) {
    __shared__ __attribute__((aligned(16))) float sp[NWIN];
    int b = blockIdx.x >> 4, slice = blockIdx.x & 15;
    int tid = threadIdx.x;
    for (int i = tid; i < NWIN / 4; i += 64)
        ((float4*)sp)[i] = ((const float4*)(probs + (size_t)b * NWIN))[i];
    __syncthreads();
    int w = slice * 64 + tid;
    float p = sp[w];
    int r = 0;
    for (int j = 0; j < NWIN; j += 4) {
        float4 pj = *(const float4*)&sp[j];
        r += (int)((pj.x > p) || (pj.x == p && (j + 0) < w));
        r += (int)((pj.y > p) || (pj.y == p && (j + 1) < w));
        r += (int)((pj.z > p) || (pj.z == p && (j + 2) < w));
        r += (int)((pj.w > p) || (pj.w == p && (j + 3) < w));
    }
    rank[b * NWIN + w] = r;
    if (r < TOPK) { sel[b * TOPK + r] = w; rw[b * TOPK + r] = p; }
}

// softplus via hardware exp/log: max(v,0) + log(1 + exp(-|v|)), arg in (1,2]
__device__ __forceinline__ float softplus_f(float v) {
    return fmaxf(v, 0.f) + __logf(1.0f + __expf(-fabsf(v)));
}

// per-sub-chunk selected-window lookup: sub-chunk = exactly one scan window
__device__ __forceinline__ int subchunk_wsel(const int* sel, int b, int k, int t, int si) {
    int qscan = 2 * t + si;
    if (k >= 2) qscan = 255 - qscan;
    int selidx = (k & 1) ? (((qscan & 15) << 4) | (qscan >> 4)) : qscan;
    return sel[b * TOPK + selidx];
}

// gather one selected 7x7 window (49 scan positions x 24 channels) into LDS
__device__ __forceinline__ void gather_win(float (*sxs)[LCP], const float* __restrict__ x,
                                           int b, int k, int wsel, int tid) {
    const float* gbase = x + (((size_t)b * CC + k) * HH + (wsel >> 5) * 7) * HH + (wsel & 31) * 7;
    for (int idx = tid; idx < PERK * 49; idx += 384) {
        int d2 = idx / 49, j = idx - d2 * 49;
        int pix = (k >= 2) ? 48 - j : j;
        int q7 = pix / 7, r7 = pix - q7 * 7;
        int wi = (k & 1) ? r7 : q7;
        int wj = (k & 1) ? q7 : r7;
        sxs[d2][j] = gbase[(size_t)d2 * 4 * HH * HH + wi * HH + wj];
    }
}

// -------- K4: phase-1 chunk scan: per-chunk (P = prod a, S = local state) --------
__global__ __launch_bounds__(384, 4) void k_phase1(
        const float* __restrict__ x, const float* __restrict__ wcomb,
        const float* __restrict__ dtb, const float* __restrict__ alogs,
        const int* __restrict__ sel,
        float* __restrict__ carrP, float* __restrict__ carrS) {
    __shared__ __attribute__((aligned(16))) float sxsA[PERK][LCP];
    __shared__ __attribute__((aligned(16))) float sxsB[PERK][LCP];
    __shared__ __attribute__((aligned(16))) float sdelta[PERK][LCP];
    __shared__ __attribute__((aligned(16))) float sB[DST][LCP];
    __shared__ float swt[40 * PERK];
    __shared__ float sbias[PERK];
    int blk = blockIdx.x;               // bk*TCH + t
    int t = blk % TCH; int bk = blk / TCH; int k = bk & 3; int b = bk >> 2;
    int tid = threadIdx.x;
    // issue both sub-chunk gathers up front (latency overlaps W-load + first proj)
    gather_win(sxsA, x, b, k, subchunk_wsel(sel, b, k, t, 0), tid);
    gather_win(sxsB, x, b, k, subchunk_wsel(sel, b, k, t, 1), tid);
    for (int i = tid; i < 40 * PERK; i += 384) swt[i] = wcomb[k * (56 * PERK) + i];
    if (tid < PERK) sbias[tid] = dtb[k * PERK + tid];
    if (tid < 256) {                    // zero pad columns 49..51 (never overwritten)
        int r = tid / 3, j = 49 + tid % 3;
        if (r < 24) sxsA[r][j] = 0.f;
        else if (r < 48) sxsB[r - 24][j] = 0.f;
        else if (r < 72) sdelta[r - 48][j] = 0.f;
        else if (r < 88) sB[r - 72][j] = 0.f;
    }
    int d = tid >> 4, s = tid & 15;
    float A = -__expf(alogs[(k * PERK + d) * DST + s]);
    float P = 1.f, S = 0.f;
    __syncthreads();
    #pragma unroll 1
    for (int si = 0; si < 2; ++si) {
        float (*sxs)[LCP] = si ? sxsB : sxsA;
        // fused projection: rows 0..23 -> softplus(Weff*xs+bias)=delta, rows 24..39 -> B
        for (int idx = tid; idx < 40 * NG; idx += 384) {
            int row = idx / NG, g = idx - row * NG; int j = g * 4;
            float bs = (row < PERK) ? sbias[row] : 0.f;
            float ax = bs, ay = bs, az = bs, aw = bs;
            #pragma unroll
            for (int d2 = 0; d2 < PERK; ++d2) {
                float w = swt[row * PERK + d2];
                float4 v = *(const float4*)&sxs[d2][j];
                ax += w * v.x; ay += w * v.y; az += w * v.z; aw += w * v.w;
            }
            float* dst;
            if (row < PERK) {
                ax = softplus_f(ax); ay = softplus_f(ay); az = softplus_f(az); aw = softplus_f(aw);
                dst = &sdelta[row][j];
            } else dst = &sB[row - PERK][j];
            if (g < 12) { float4 o = {ax, ay, az, aw}; *(float4*)dst = o; }
            else dst[0] = ax;
        }
        __syncthreads();
        for (int g = 0; g < NG; ++g) {
            int j = g * 4;
            float4 dl4 = *(const float4*)&sdelta[d][j];   // pads = 0
            float4 xs4 = *(const float4*)&sxs[d][j];      // pads = 0
            float4 B4  = *(const float4*)&sB[s][j];       // pads = 0
            float aa;
            aa = __expf(dl4.x * A); S = aa * S + (dl4.x * xs4.x) * B4.x; P *= aa;
            aa = __expf(dl4.y * A); S = aa * S + (dl4.y * xs4.y) * B4.y; P *= aa;
            aa = __expf(dl4.z * A); S = aa * S + (dl4.z * xs4.z) * B4.z; P *= aa;
            aa = __expf(dl4.w * A); S = aa * S + (dl4.w * xs4.w) * B4.w; P *= aa;
        }
        __syncthreads();   // protect sdelta/sB before next projection overwrites
    }
    size_t cidx = (size_t)blk * 384 + tid;
    carrP[cidx] = P; carrS[cidx] = S;
}

// -------- K5: carry scan across chunks (hin may alias carrP: read-before-write) --------
__global__ void k_carry(const float* carrP, const float* carrS, float* hin) {
    int gid = blockIdx.x * blockDim.x + threadIdx.x;   // 12288
    int bk = gid / 384, ds = gid - bk * 384;
    float Hv = 0.f;
    for (int t = 0; t < TCH; ++t) {
        size_t idx = ((size_t)bk * TCH + t) * 384 + ds;
        float pv = carrP[idx], sv = carrS[idx];
        hin[idx] = Hv;
        Hv = pv * Hv + sv;
    }
}

// -------- K6: base output: x*(1+p) unselected, x selected --------
__global__ __launch_bounds__(64) void k_base(const float* __restrict__ x,
        const float* __restrict__ probs, const int* __restrict__ rank,
        float* __restrict__ out) {
    int wr = blockIdx.x % NHW; int bc = blockIdx.x / NHW;
    int b = bc / CC;
    __shared__ float buf[7 * HH];
    __shared__ float fmul[NHW];
    int tid = threadIdx.x;
    const float* xp = x + ((size_t)bc * HH + wr * 7) * HH;
    for (int i = tid; i < 7 * HH; i += 64) buf[i] = xp[i];
    if (tid < NHW) {
        int w = wr * NHW + tid;
        fmul[tid] = (rank[b * NWIN + w] < TOPK) ? 1.0f : (1.0f + probs[b * NWIN + w]);
    }
    __syncthreads();
    int c = bc - b * CC;
    for (int idx = tid; idx < NHW * 49; idx += 64) {
        int wc = idx / 49, r = idx - wc * 49;
        int ri = r / 7, rj = r - ri * 7;
        float v = buf[ri * HH + wc * 7 + rj];
        int w = wr * NHW + wc;
        out[(((size_t)b * NWIN + w) * CC + c) * 49 + r] = v * fmul[wc];
    }
}

// -------- K7: phase-3 scan with carry-in; y written DENSE in scan order (coalesced) --------
__global__ __launch_bounds__(384, 4) void k_scan(
        const float* __restrict__ x, const float* __restrict__ wcomb,
        const float* __restrict__ dtb, const float* __restrict__ alogs,
        const float* __restrict__ dsv, const int* __restrict__ sel,
        const float* __restrict__ hin, float* __restrict__ yws) {
    __shared__ __attribute__((aligned(16))) float sxsA[PERK][LCP];
    __shared__ __attribute__((aligned(16))) float sxsB[PERK][LCP];
    __shared__ __attribute__((aligned(16))) float sdelta[PERK][LCP];  // doubles as y after recurrence
    __shared__ __attribute__((aligned(16))) float sB[DST][LCP];
    __shared__ __attribute__((aligned(16))) float sC[DST][LCP];
    __shared__ float swt[56 * PERK];
    __shared__ float sbias[PERK];
    int blk = blockIdx.x;
    int t = blk % TCH; int bk = blk / TCH; int k = bk & 3; int b = bk >> 2;
    int tid = threadIdx.x;
    // issue both sub-chunk gathers up front
    gather_win(sxsA, x, b, k, subchunk_wsel(sel, b, k, t, 0), tid);
    gather_win(sxsB, x, b, k, subchunk_wsel(sel, b, k, t, 1), tid);
    for (int i = tid; i < 56 * PERK; i += 384) swt[i] = wcomb[k * (56 * PERK) + i];
    if (tid < PERK) sbias[tid] = dtb[k * PERK + tid];
    if (tid < 312) {                    // zero pad columns 49..51
        int r = tid / 3, j = 49 + tid % 3;
        if (r < 24) sxsA[r][j] = 0.f;
        else if (r < 48) sxsB[r - 24][j] = 0.f;
        else if (r < 72) sdelta[r - 48][j] = 0.f;
        else if (r < 88) sB[r - 72][j] = 0.f;
        else if (r < 104) sC[r - 88][j] = 0.f;
    }
    int d = tid >> 4, s = tid & 15;
    float A = -__expf(alogs[(k * PERK + d) * DST + s]);
    float Dsr = dsv[k * PERK + d];
    size_t cidx = (size_t)blk * 384 + tid;
    float h = hin[cidx];
    __syncthreads();
    #pragma unroll 1
    for (int si = 0; si < 2; ++si) {
        float (*sxs)[LCP] = si ? sxsB : sxsA;
        int l0 = t * LC + si * 49;
        // fused projection: 0..23 delta (softplus), 24..39 B, 40..55 C
        for (int idx = tid; idx < 56 * NG; idx += 384) {
            int row = idx / NG, g = idx - row * NG; int j = g * 4;
            float bs = (row < PERK) ? sbias[row] : 0.f;
            float ax = bs, ay = bs, az = bs, aw = bs;
            #pragma unroll
            for (int d2 = 0; d2 < PERK; ++d2) {
                float w = swt[row * PERK + d2];
                float4 v = *(const float4*)&sxs[d2][j];
                ax += w * v.x; ay += w * v.y; az += w * v.z; aw += w * v.w;
            }
            float* dst;
            if (row < PERK) {
                ax = softplus_f(ax); ay = softplus_f(ay); az = softplus_f(az); aw = softplus_f(aw);
                dst = &sdelta[row][j];
            } else if (row < PERK + DST) dst = &sB[row - PERK][j];
            else dst = &sC[row - PERK - DST][j];
            if (g < 12) { float4 o = {ax, ay, az, aw}; *(float4*)dst = o; }
            else dst[0] = ax;
        }
        __syncthreads();
        for (int g = 0; g < NG; ++g) {
            int j = g * 4;
            float4 dl4 = *(const float4*)&sdelta[d][j];
            float4 xs4 = *(const float4*)&sxs[d][j];
            float4 B4  = *(const float4*)&sB[s][j];
            float4 C4  = *(const float4*)&sC[s][j];
            float aa, part;
            aa = __expf(dl4.x * A); h = aa * h + (dl4.x * xs4.x) * B4.x;
            part = h * C4.x;
            ROR_ADD(part, 0x121); ROR_ADD(part, 0x122); ROR_ADD(part, 0x124); ROR_ADD(part, 0x128);
            if (s == 0) sdelta[d][j] = part + xs4.x * Dsr;
            aa = __expf(dl4.y * A); h = aa * h + (dl4.y * xs4.y) * B4.y;
            part = h * C4.y;
            ROR_ADD(part, 0x121); ROR_ADD(part, 0x122); ROR_ADD(part, 0x124); ROR_ADD(part, 0x128);
            if (s == 0 && j + 1 < 49) sdelta[d][j + 1] = part + xs4.y * Dsr;
            aa = __expf(dl4.z * A); h = aa * h + (dl4.z * xs4.z) * B4.z;
            part = h * C4.z;
            ROR_ADD(part, 0x121); ROR_ADD(part, 0x122); ROR_ADD(part, 0x124); ROR_ADD(part, 0x128);
            if (s == 0 && j + 2 < 49) sdelta[d][j + 2] = part + xs4.z * Dsr;
            aa = __expf(dl4.w * A); h = aa * h + (dl4.w * xs4.w) * B4.w;
            part = h * C4.w;
            ROR_ADD(part, 0x121); ROR_ADD(part, 0x122); ROR_ADD(part, 0x124); ROR_ADD(part, 0x128);
            if (s == 0 && j + 3 < 49) sdelta[d][j + 3] = part + xs4.w * Dsr;
        }
        __syncthreads();
        // dense coalesced write: yws[bk][l0+j][d2] — 4704 contiguous floats per sub-chunk
        float* ybase = yws + ((size_t)bk * LL + l0) * PERK;
        for (int idx = tid; idx < PERK * 49; idx += 384) {
            int j = idx / PERK, d2 = idx - j * PERK;
            ybase[idx] = sdelta[d2][j];
        }
        __syncthreads();   // protect sdelta before next projection overwrites
    }
}

// -------- K8: per-selected-window gather of y + contiguous RMW into out --------
__global__ __launch_bounds__(256) void k_yadd(const float* __restrict__ yws,
        const int* __restrict__ sel, const float* __restrict__ rw,
        float* __restrict__ out) {
    __shared__ float ytile[CC * 49];
    int qo = blockIdx.x & 255; int b = blockIdx.x >> 8;
    int wsel = sel[b * TOPK + qo];
    float p = rw[b * TOPK + qo];
    for (int idx = threadIdx.x; idx < CC * 49; idx += 256) {
        int k = idx / 1176; int r1 = idx - k * 1176;
        int u = r1 / 168;   int r2 = r1 - u * 168;
        int wj = r2 / 24;   int d = r2 - wj * 24;
        int rest = qo * 7 + u;
        int b2 = rest & 15; int aw = rest >> 4;
        int wi = aw % 7;    int a = aw / 7;
        int q   = (k & 1) ? (b2 * 16 + a) : (a * 16 + b2);
        int pix = (k & 1) ? (wj * 7 + wi) : (wi * 7 + wj);
        int uu = q * 49 + pix;
        int l = (k >= 2) ? (LL - 1 - uu) : uu;
        ytile[(k * PERK + d) * 49 + u * 7 + wj] = yws[((size_t)(b * 4 + k) * LL + l) * PERK + d];
    }
    __syncthreads();
    float* ob = out + ((size_t)(b * NWIN + wsel) * CC) * 49;
    for (int e = threadIdx.x; e < CC * 49; e += 256) ob[e] += p * ytile[e];
}

extern "C" void kernel_launch(void* const* d_in, const int* in_sizes, int n_in,
                              void* d_out, int out_size, void* d_ws, size_t ws_size,
                              hipStream_t stream) {
    const float* x   = (const float*)d_in[0];
    const float* w1  = (const float*)d_in[1];
    const float* b1  = (const float*)d_in[2];
    const float* w2  = (const float*)d_in[3];
    const float* b2  = (const float*)d_in[4];
    const float* xpw = (const float*)d_in[5];
    const float* dtw = (const float*)d_in[6];
    const float* dtb = (const float*)d_in[7];
    const float* alg = (const float*)d_in[8];
    const float* dsv = (const float*)d_in[9];
    float* out = (float*)d_out;
    float* ws  = (float*)d_ws;

    float* pooled = ws + OFF_POOL;
    float* logits = ws + OFF_LOG;
    float* probs  = ws + OFF_PROB;
    float* rwv    = ws + OFF_RW;
    int*   rank   = (int*)(ws + OFF_RANK);
    int*   sel    = (int*)(ws + OFF_SEL);
    float* wcomb  = ws + OFF_WEFF;
    float* cP  = ws + OFF_CP;       // also hin after k_carry
    float* cS  = ws + OFF_CS;
    float* yws = ws + OFF_YWS;

    k_weff  <<<(4 * 56 * PERK + 255) / 256, 256, 0, stream>>>(xpw, dtw, wcomb);
    k_pool  <<<BBATCH * CC, 256, 0, stream>>>(x, pooled);
    k_router<<<BBATCH * NWIN / 256, 256, 0, stream>>>(pooled, w1, b1, w2, b2, logits);
    k_soft  <<<BBATCH, 1024, 0, stream>>>(logits, probs);
    k_rank2 <<<BBATCH * 16, 64, 0, stream>>>(probs, rwv, rank, sel);
    k_phase1<<<NBK * TCH, 384, 0, stream>>>(x, wcomb, dtb, alg, sel, cP, cS);
    k_carry <<<48, 256, 0, stream>>>(cP, cS, cP);     // hin aliases cP (read-before-write)
    k_base  <<<BBATCH * CC * NHW, 64, 0, stream>>>(x, probs, rank, out);
    k_scan  <<<NBK * TCH, 384, 0, stream>>>(x, wcomb, dtb, alg, dsv, sel, cP, yws);
    k_yadd  <<<BBATCH * TOPK, 256, 0, stream>>>(yws, sel, rwv, out);
}

// Round 7
// 571.676 us; speedup vs baseline: 1.0216x; 1.0216x over previous
//
#include <hip/hip_runtime.h>
#include <math.h>

// Problem constants
#define BBATCH 8
#define CC 96
#define HH 224
#define NHW 32            // 224/7 windows per side
#define NWIN 1024
#define TOPK 256
#define PERK 24
#define DST 16
#define DTR 6
#define LL 12544          // 256*49
#define LCP 52            // padded row length (49 used + 3 zero pad)
#define NG 13             // float4 groups per row
#define TCH 256           // one chunk = ONE scan window (49 steps)
#define NBK 32            // B*4 directions

// workspace offsets (floats) — total 16,745,728 floats = 67.0 MB
#define OFF_POOL 0
#define OFF_LOG  786432
#define OFF_PROB 794624
#define OFF_RW   802816
#define OFF_RANK 804864
#define OFF_SEL  813056
#define OFF_WEFF 815104
#define OFF_CP   820480      // 3,145,728 floats; ALSO reused as hin (read-before-write in k_carry)
#define OFF_CS   3966208     // 3,145,728 floats
#define OFF_YWS  7111936     // 9,633,792 floats: y_ws[bk][l][d], d innermost

// DPP row_ror:N add — 16-lane full-sum reduction on the VALU pipe (not DS)
#define ROR_ADD(v, CTRL) \
    v += __int_as_float(__builtin_amdgcn_update_dpp(0, __float_as_int(v), CTRL, 0xf, 0xf, true))

// -------- K0: fold dt_proj into x_proj: Wcomb[k][56][24] --------
__global__ void k_weff(const float* __restrict__ xpw, const float* __restrict__ dtw,
                       float* __restrict__ wcomb) {
    int i = blockIdx.x * blockDim.x + threadIdx.x;
    if (i >= 4 * 56 * PERK) return;
    int k = i / (56 * PERK), rem = i - k * (56 * PERK);
    int row = rem / PERK, c = rem - row * PERK;
    float v;
    if (row < PERK) {
        v = 0.f;
        #pragma unroll
        for (int r = 0; r < DTR; ++r)
            v += dtw[(k * PERK + row) * DTR + r] * xpw[(k * 38 + r) * PERK + c];
    } else {
        v = xpw[(k * 38 + (row - PERK + DTR)) * PERK + c];
    }
    wcomb[i] = v;
}

// -------- K1: window pooling: pooledT[b][c][w] --------
__global__ void k_pool(const float* __restrict__ x, float* __restrict__ pooled) {
    int bc = blockIdx.x;                 // b*96+c
    const float* xp = x + (size_t)bc * HH * HH;
    float* pp = pooled + (size_t)bc * NWIN;
    for (int w = threadIdx.x; w < NWIN; w += blockDim.x) {
        int wr = w >> 5, wc = w & 31;
        const float* base = xp + (wr * 7) * HH + wc * 7;
        float s = 0.f;
        #pragma unroll
        for (int i = 0; i < 7; ++i) {
            #pragma unroll
            for (int j = 0; j < 7; ++j) s += base[i * HH + j];
        }
        pp[w] = s * (1.0f / 49.0f);
    }
}

// -------- K2: router MLP -> logits --------
__global__ void k_router(const float* __restrict__ pooled,
                         const float* __restrict__ w1, const float* __restrict__ b1,
                         const float* __restrict__ w2, const float* __restrict__ b2,
                         float* __restrict__ logits) {
    __shared__ float sw1[PERK * CC];
    __shared__ float sb1[PERK];
    __shared__ float sw2[PERK];
    for (int i = threadIdx.x; i < PERK * CC; i += blockDim.x) sw1[i] = w1[i];
    if (threadIdx.x < PERK) { sb1[threadIdx.x] = b1[threadIdx.x]; sw2[threadIdx.x] = w2[threadIdx.x]; }
    __syncthreads();
    int gid = blockIdx.x * blockDim.x + threadIdx.x;   // 8192 threads
    int b = gid >> 10, w = gid & 1023;
    float hid[PERK];
    #pragma unroll
    for (int j = 0; j < PERK; ++j) hid[j] = sb1[j];
    const float* pp = pooled + (size_t)b * CC * NWIN + w;
    for (int c = 0; c < CC; ++c) {
        float pv = pp[(size_t)c * NWIN];
        #pragma unroll
        for (int j = 0; j < PERK; ++j) hid[j] += pv * sw1[j * CC + c];
    }
    float lg = b2[0];
    #pragma unroll
    for (int j = 0; j < PERK; ++j) {
        float hv = hid[j];
        float g = 0.5f * hv * (1.0f + erff(hv * 0.7071067811865476f));
        lg += g * sw2[j];
    }
    logits[gid] = lg;
}

// -------- K3a: softmax over 1024 windows --------
__global__ void k_soft(const float* __restrict__ logits, float* __restrict__ probs) {
    __shared__ float red[NWIN];
    int b = blockIdx.x, t = threadIdx.x;
    float lg = logits[b * NWIN + t];
    red[t] = lg; __syncthreads();
    for (int o = 512; o > 0; o >>= 1) { if (t < o) red[t] = fmaxf(red[t], red[t + o]); __syncthreads(); }
    float mx = red[0]; __syncthreads();
    float e = expf(lg - mx);
    red[t] = e; __syncthreads();
    for (int o = 512; o > 0; o >>= 1) { if (t < o) red[t] += red[t + o]; __syncthreads(); }
    probs[b * NWIN + t] = e / red[0];
}

// -------- K3b: stable descending rank (distributed over 128 blocks) --------
__global__ __launch_bounds__(64) void k_rank2(const float* __restrict__ probs,
        float* __restrict__ rw, int* __restrict__ rank, int* __restrict__ sel) {
    __shared__ __attribute__((aligned(16))) float sp[NWIN];
    int b = blockIdx.x >> 4, slice = blockIdx.x & 15;
    int tid = threadIdx.x;
    for (int i = tid; i < NWIN / 4; i += 64)
        ((float4*)sp)[i] = ((const float4*)(probs + (size_t)b * NWIN))[i];
    __syncthreads();
    int w = slice * 64 + tid;
    float p = sp[w];
    int r = 0;
    for (int j = 0; j < NWIN; j += 4) {
        float4 pj = *(const float4*)&sp[j];
        r += (int)((pj.x > p) || (pj.x == p && (j + 0) < w));
        r += (int)((pj.y > p) || (pj.y == p && (j + 1) < w));
        r += (int)((pj.z > p) || (pj.z == p && (j + 2) < w));
        r += (int)((pj.w > p) || (pj.w == p && (j + 3) < w));
    }
    rank[b * NWIN + w] = r;
    if (r < TOPK) { sel[b * TOPK + r] = w; rw[b * TOPK + r] = p; }
}

// softplus via hardware exp/log: max(v,0) + log(1 + exp(-|v|)), arg in (1,2]
__device__ __forceinline__ float softplus_f(float v) {
    return fmaxf(v, 0.f) + __logf(1.0f + __expf(-fabsf(v)));
}

// chunk t (= scan-window index) -> selected-window id
__device__ __forceinline__ int window_wsel(const int* sel, int b, int k, int t) {
    int qscan = (k >= 2) ? (255 - t) : t;
    int selidx = (k & 1) ? (((qscan & 15) << 4) | (qscan >> 4)) : qscan;
    return sel[b * TOPK + selidx];
}

// gather one selected 7x7 window (49 scan positions x 24 channels) into LDS
__device__ __forceinline__ void gather_win(float (*sxs)[LCP], const float* __restrict__ x,
                                           int b, int k, int wsel, int tid) {
    const float* gbase = x + (((size_t)b * CC + k) * HH + (wsel >> 5) * 7) * HH + (wsel & 31) * 7;
    for (int idx = tid; idx < PERK * 49; idx += 384) {
        int d2 = idx / 49, j = idx - d2 * 49;
        int pix = (k >= 2) ? 48 - j : j;
        int q7 = pix / 7, r7 = pix - q7 * 7;
        int wi = (k & 1) ? r7 : q7;
        int wj = (k & 1) ? q7 : r7;
        sxs[d2][j] = gbase[(size_t)d2 * 4 * HH * HH + wi * HH + wj];
    }
}

// -------- K4: phase-1 per-window scan: (P = prod a, S = local state) --------
__global__ __launch_bounds__(384, 4) void k_phase1(
        const float* __restrict__ x, const float* __restrict__ wcomb,
        const float* __restrict__ dtb, const float* __restrict__ alogs,
        const int* __restrict__ sel,
        float* __restrict__ carrP, float* __restrict__ carrS) {
    __shared__ __attribute__((aligned(16))) float sxs[PERK][LCP];
    __shared__ __attribute__((aligned(16))) float sdelta[PERK][LCP];
    __shared__ __attribute__((aligned(16))) float sB[DST][LCP];
    __shared__ float swt[40 * PERK];
    __shared__ float sbias[PERK];
    int blk = blockIdx.x;               // bk*TCH + t
    int t = blk & 255; int bk = blk >> 8; int k = bk & 3; int b = bk >> 2;
    int tid = threadIdx.x;
    gather_win(sxs, x, b, k, window_wsel(sel, b, k, t), tid);
    for (int i = tid; i < 40 * PERK; i += 384) swt[i] = wcomb[k * (56 * PERK) + i];
    if (tid < PERK) sbias[tid] = dtb[k * PERK + tid];
    if (tid < 192) {                    // zero pad columns 49..51 (never overwritten)
        int r = tid / 3, j = 49 + tid % 3;
        if (r < 24) sxs[r][j] = 0.f;
        else if (r < 48) sdelta[r - 24][j] = 0.f;
        else sB[r - 48][j] = 0.f;
    }
    int d = tid >> 4, s = tid & 15;
    float A = -__expf(alogs[(k * PERK + d) * DST + s]);
    __syncthreads();
    // fused projection: rows 0..23 -> softplus(Weff*xs+bias)=delta, rows 24..39 -> B
    for (int idx = tid; idx < 40 * NG; idx += 384) {
        int row = idx / NG, g = idx - row * NG; int j = g * 4;
        float bs = (row < PERK) ? sbias[row] : 0.f;
        float ax = bs, ay = bs, az = bs, aw = bs;
        #pragma unroll
        for (int d2 = 0; d2 < PERK; ++d2) {
            float w = swt[row * PERK + d2];
            float4 v = *(const float4*)&sxs[d2][j];
            ax += w * v.x; ay += w * v.y; az += w * v.z; aw += w * v.w;
        }
        float* dst;
        if (row < PERK) {
            ax = softplus_f(ax); ay = softplus_f(ay); az = softplus_f(az); aw = softplus_f(aw);
            dst = &sdelta[row][j];
        } else dst = &sB[row - PERK][j];
        if (g < 12) { float4 o = {ax, ay, az, aw}; *(float4*)dst = o; }
        else dst[0] = ax;
    }
    __syncthreads();
    float P = 1.f, S = 0.f;
    for (int g = 0; g < NG; ++g) {
        int j = g * 4;
        float4 dl4 = *(const float4*)&sdelta[d][j];   // pads = 0
        float4 xs4 = *(const float4*)&sxs[d][j];      // pads = 0
        float4 B4  = *(const float4*)&sB[s][j];       // pads = 0
        float aa;
        aa = __expf(dl4.x * A); S = aa * S + (dl4.x * xs4.x) * B4.x; P *= aa;
        aa = __expf(dl4.y * A); S = aa * S + (dl4.y * xs4.y) * B4.y; P *= aa;
        aa = __expf(dl4.z * A); S = aa * S + (dl4.z * xs4.z) * B4.z; P *= aa;
        aa = __expf(dl4.w * A); S = aa * S + (dl4.w * xs4.w) * B4.w; P *= aa;
    }
    size_t cidx = (size_t)blk * 384 + tid;
    carrP[cidx] = P; carrS[cidx] = S;
}

// -------- K5: carry scan across 256 windows (hin may alias carrP: read-before-write) --------
__global__ void k_carry(const float* carrP, const float* carrS, float* hin) {
    int gid = blockIdx.x * blockDim.x + threadIdx.x;   // 12288
    int bk = gid / 384, ds = gid - bk * 384;
    float Hv = 0.f;
    for (int t = 0; t < TCH; ++t) {
        size_t idx = ((size_t)bk * TCH + t) * 384 + ds;
        float pv = carrP[idx], sv = carrS[idx];
        hin[idx] = Hv;
        Hv = pv * Hv + sv;
    }
}

// -------- K6: base output: x*(1+p) unselected, x selected --------
__global__ __launch_bounds__(64) void k_base(const float* __restrict__ x,
        const float* __restrict__ probs, const int* __restrict__ rank,
        float* __restrict__ out) {
    int wr = blockIdx.x % NHW; int bc = blockIdx.x / NHW;
    int b = bc / CC;
    __shared__ float buf[7 * HH];
    __shared__ float fmul[NHW];
    int tid = threadIdx.x;
    const float* xp = x + ((size_t)bc * HH + wr * 7) * HH;
    for (int i = tid; i < 7 * HH; i += 64) buf[i] = xp[i];
    if (tid < NHW) {
        int w = wr * NHW + tid;
        fmul[tid] = (rank[b * NWIN + w] < TOPK) ? 1.0f : (1.0f + probs[b * NWIN + w]);
    }
    __syncthreads();
    int c = bc - b * CC;
    for (int idx = tid; idx < NHW * 49; idx += 64) {
        int wc = idx / 49, r = idx - wc * 49;
        int ri = r / 7, rj = r - ri * 7;
        float v = buf[ri * HH + wc * 7 + rj];
        int w = wr * NHW + wc;
        out[(((size_t)b * NWIN + w) * CC + c) * 49 + r] = v * fmul[wc];
    }
}

// -------- K7: phase-3 per-window scan with carry-in; y written DENSE (coalesced) --------
__global__ __launch_bounds__(384, 4) void k_scan(
        const float* __restrict__ x, const float* __restrict__ wcomb,
        const float* __restrict__ dtb, const float* __restrict__ alogs,
        const float* __restrict__ dsv, const int* __restrict__ sel,
        const float* __restrict__ hin, float* __restrict__ yws) {
    __shared__ __attribute__((aligned(16))) float sxs[PERK][LCP];
    __shared__ __attribute__((aligned(16))) float sdelta[PERK][LCP];  // doubles as y after recurrence
    __shared__ __attribute__((aligned(16))) float sB[DST][LCP];
    __shared__ __attribute__((aligned(16))) float sC[DST][LCP];
    __shared__ float swt[56 * PERK];
    __shared__ float sbias[PERK];
    int blk = blockIdx.x;
    int t = blk & 255; int bk = blk >> 8; int k = bk & 3; int b = bk >> 2;
    int tid = threadIdx.x;
    gather_win(sxs, x, b, k, window_wsel(sel, b, k, t), tid);
    for (int i = tid; i < 56 * PERK; i += 384) swt[i] = wcomb[k * (56 * PERK) + i];
    if (tid < PERK) sbias[tid] = dtb[k * PERK + tid];
    if (tid < 240) {                    // zero pad columns 49..51
        int r = tid / 3, j = 49 + tid % 3;
        if (r < 24) sxs[r][j] = 0.f;
        else if (r < 48) sdelta[r - 24][j] = 0.f;
        else if (r < 64) sB[r - 48][j] = 0.f;
        else sC[r - 64][j] = 0.f;
    }
    int d = tid >> 4, s = tid & 15;
    float A = -__expf(alogs[(k * PERK + d) * DST + s]);
    float Dsr = dsv[k * PERK + d];
    size_t cidx = (size_t)blk * 384 + tid;
    float h = hin[cidx];
    __syncthreads();
    // fused projection: 0..23 delta (softplus), 24..39 B, 40..55 C
    for (int idx = tid; idx < 56 * NG; idx += 384) {
        int row = idx / NG, g = idx - row * NG; int j = g * 4;
        float bs = (row < PERK) ? sbias[row] : 0.f;
        float ax = bs, ay = bs, az = bs, aw = bs;
        #pragma unroll
        for (int d2 = 0; d2 < PERK; ++d2) {
            float w = swt[row * PERK + d2];
            float4 v = *(const float4*)&sxs[d2][j];
            ax += w * v.x; ay += w * v.y; az += w * v.z; aw += w * v.w;
        }
        float* dst;
        if (row < PERK) {
            ax = softplus_f(ax); ay = softplus_f(ay); az = softplus_f(az); aw = softplus_f(aw);
            dst = &sdelta[row][j];
        } else if (row < PERK + DST) dst = &sB[row - PERK][j];
        else dst = &sC[row - PERK - DST][j];
        if (g < 12) { float4 o = {ax, ay, az, aw}; *(float4*)dst = o; }
        else dst[0] = ax;
    }
    __syncthreads();
    for (int g = 0; g < NG; ++g) {
        int j = g * 4;
        float4 dl4 = *(const float4*)&sdelta[d][j];
        float4 xs4 = *(const float4*)&sxs[d][j];
        float4 B4  = *(const float4*)&sB[s][j];
        float4 C4  = *(const float4*)&sC[s][j];
        float aa, part;
        aa = __expf(dl4.x * A); h = aa * h + (dl4.x * xs4.x) * B4.x;
        part = h * C4.x;
        ROR_ADD(part, 0x121); ROR_ADD(part, 0x122); ROR_ADD(part, 0x124); ROR_ADD(part, 0x128);
        if (s == 0) sdelta[d][j] = part + xs4.x * Dsr;
        aa = __expf(dl4.y * A); h = aa * h + (dl4.y * xs4.y) * B4.y;
        part = h * C4.y;
        ROR_ADD(part, 0x121); ROR_ADD(part, 0x122); ROR_ADD(part, 0x124); ROR_ADD(part, 0x128);
        if (s == 0 && j + 1 < 49) sdelta[d][j + 1] = part + xs4.y * Dsr;
        aa = __expf(dl4.z * A); h = aa * h + (dl4.z * xs4.z) * B4.z;
        part = h * C4.z;
        ROR_ADD(part, 0x121); ROR_ADD(part, 0x122); ROR_ADD(part, 0x124); ROR_ADD(part, 0x128);
        if (s == 0 && j + 2 < 49) sdelta[d][j + 2] = part + xs4.z * Dsr;
        aa = __expf(dl4.w * A); h = aa * h + (dl4.w * xs4.w) * B4.w;
        part = h * C4.w;
        ROR_ADD(part, 0x121); ROR_ADD(part, 0x122); ROR_ADD(part, 0x124); ROR_ADD(part, 0x128);
        if (s == 0 && j + 3 < 49) sdelta[d][j + 3] = part + xs4.w * Dsr;
    }
    __syncthreads();
    // dense coalesced write: yws[bk][t*49 + j][d2] — 1176 contiguous floats
    float* ybase = yws + ((size_t)bk * LL + t * 49) * PERK;
    for (int idx = tid; idx < PERK * 49; idx += 384) {
        int j = idx / PERK, d2 = idx - j * PERK;
        ybase[idx] = sdelta[d2][j];
    }
}

// -------- K8: per-selected-window gather of y + contiguous RMW into out --------
__global__ __launch_bounds__(256) void k_yadd(const float* __restrict__ yws,
        const int* __restrict__ sel, const float* __restrict__ rw,
        float* __restrict__ out) {
    __shared__ float ytile[CC * 49];
    int qo = blockIdx.x & 255; int b = blockIdx.x >> 8;
    int wsel = sel[b * TOPK + qo];
    float p = rw[b * TOPK + qo];
    for (int idx = threadIdx.x; idx < CC * 49; idx += 256) {
        int k = idx / 1176; int r1 = idx - k * 1176;
        int u = r1 / 168;   int r2 = r1 - u * 168;
        int wj = r2 / 24;   int d = r2 - wj * 24;
        int rest = qo * 7 + u;
        int b2 = rest & 15; int aw = rest >> 4;
        int wi = aw % 7;    int a = aw / 7;
        int q   = (k & 1) ? (b2 * 16 + a) : (a * 16 + b2);
        int pix = (k & 1) ? (wj * 7 + wi) : (wi * 7 + wj);
        int uu = q * 49 + pix;
        int l = (k >= 2) ? (LL - 1 - uu) : uu;
        ytile[(k * PERK + d) * 49 + u * 7 + wj] = yws[((size_t)(b * 4 + k) * LL + l) * PERK + d];
    }
    __syncthreads();
    float* ob = out + ((size_t)(b * NWIN + wsel) * CC) * 49;
    for (int e = threadIdx.x; e < CC * 49; e += 256) ob[e] += p * ytile[e];
}

extern "C" void kernel_launch(void* const* d_in, const int* in_sizes, int n_in,
                              void* d_out, int out_size, void* d_ws, size_t ws_size,
                              hipStream_t stream) {
    const float* x   = (const float*)d_in[0];
    const float* w1  = (const float*)d_in[1];
    const float* b1  = (const float*)d_in[2];
    const float* w2  = (const float*)d_in[3];
    const float* b2  = (const float*)d_in[4];
    const float* xpw = (const float*)d_in[5];
    const float* dtw = (const float*)d_in[6];
    const float* dtb = (const float*)d_in[7];
    const float* alg = (const float*)d_in[8];
    const float* dsv = (const float*)d_in[9];
    float* out = (float*)d_out;
    float* ws  = (float*)d_ws;

    float* pooled = ws + OFF_POOL;
    float* logits = ws + OFF_LOG;
    float* probs  = ws + OFF_PROB;
    float* rwv    = ws + OFF_RW;
    int*   rank   = (int*)(ws + OFF_RANK);
    int*   sel    = (int*)(ws + OFF_SEL);
    float* wcomb  = ws + OFF_WEFF;
    float* cP  = ws + OFF_CP;       // also hin after k_carry
    float* cS  = ws + OFF_CS;
    float* yws = ws + OFF_YWS;

    k_weff  <<<(4 * 56 * PERK + 255) / 256, 256, 0, stream>>>(xpw, dtw, wcomb);
    k_pool  <<<BBATCH * CC, 256, 0, stream>>>(x, pooled);
    k_router<<<BBATCH * NWIN / 256, 256, 0, stream>>>(pooled, w1, b1, w2, b2, logits);
    k_soft  <<<BBATCH, 1024, 0, stream>>>(logits, probs);
    k_rank2 <<<BBATCH * 16, 64, 0, stream>>>(probs, rwv, rank, sel);
    k_phase1<<<NBK * TCH, 384, 0, stream>>>(x, wcomb, dtb, alg, sel, cP, cS);
    k_carry <<<48, 256, 0, stream>>>(cP, cS, cP);     // hin aliases cP (read-before-write)
    k_base  <<<BBATCH * CC * NHW, 64, 0, stream>>>(x, probs, rank, out);
    k_scan  <<<NBK * TCH, 384, 0, stream>>>(x, wcomb, dtb, alg, dsv, sel, cP, yws);
    k_yadd  <<<BBATCH * TOPK, 256, 0, stream>>>(yws, sel, rwv, out);
}

// Round 8
// 551.092 us; speedup vs baseline: 1.0598x; 1.0374x over previous
//
#include <hip/hip_runtime.h>
#include <math.h>

// Problem constants
#define BBATCH 8
#define CC 96
#define HH 224
#define NHW 32            // 224/7 windows per side
#define NWIN 1024
#define TOPK 256
#define PERK 24
#define DST 16
#define DTR 6
#define LL 12544          // 256*49
#define LCP 52            // padded row length (49 used + 3 zero pad)
#define NG 13             // float4 groups per row
#define TCH 256           // one chunk = ONE scan window (49 steps)
#define NBK 32            // B*4 directions
#define WST 4160          // staging floats per window: 80 rows x 52

// workspace offsets (floats)
#define OFF_POOL 0
#define OFF_LOG  786432
#define OFF_PROB 794624
#define OFF_RW   802816
#define OFF_RANK 804864
#define OFF_SEL  813056
#define OFF_WEFF 815104
#define OFF_CP   820480      // 3,145,728; reused as hin (read-before-write in k_carry)
#define OFF_CS   3966208     // 3,145,728
#define OFF_STG  7111936     // big path: 8192*4160 = 34,078,720 floats (y aliased into head)
#define OFF_YWS  7111936     // fallback path: 9,633,792 floats
#define NEED_BIG ((size_t)41190656 * 4)   // 164.8 MB

// DPP row_ror:N add — 16-lane full-sum reduction on the VALU pipe (not DS)
#define ROR_ADD(v, CTRL) \
    v += __int_as_float(__builtin_amdgcn_update_dpp(0, __float_as_int(v), CTRL, 0xf, 0xf, true))

// -------- K0: fold dt_proj into x_proj: Wcomb[k][56][24] --------
__global__ void k_weff(const float* __restrict__ xpw, const float* __restrict__ dtw,
                       float* __restrict__ wcomb) {
    int i = blockIdx.x * blockDim.x + threadIdx.x;
    if (i >= 4 * 56 * PERK) return;
    int k = i / (56 * PERK), rem = i - k * (56 * PERK);
    int row = rem / PERK, c = rem - row * PERK;
    float v;
    if (row < PERK) {
        v = 0.f;
        #pragma unroll
        for (int r = 0; r < DTR; ++r)
            v += dtw[(k * PERK + row) * DTR + r] * xpw[(k * 38 + r) * PERK + c];
    } else {
        v = xpw[(k * 38 + (row - PERK + DTR)) * PERK + c];
    }
    wcomb[i] = v;
}

// -------- K1: window pooling: pooledT[b][c][w] --------
__global__ void k_pool(const float* __restrict__ x, float* __restrict__ pooled) {
    int bc = blockIdx.x;                 // b*96+c
    const float* xp = x + (size_t)bc * HH * HH;
    float* pp = pooled + (size_t)bc * NWIN;
    for (int w = threadIdx.x; w < NWIN; w += blockDim.x) {
        int wr = w >> 5, wc = w & 31;
        const float* base = xp + (wr * 7) * HH + wc * 7;
        float s = 0.f;
        #pragma unroll
        for (int i = 0; i < 7; ++i) {
            #pragma unroll
            for (int j = 0; j < 7; ++j) s += base[i * HH + j];
        }
        pp[w] = s * (1.0f / 49.0f);
    }
}

// -------- K2: router MLP -> logits --------
__global__ void k_router(const float* __restrict__ pooled,
                         const float* __restrict__ w1, const float* __restrict__ b1,
                         const float* __restrict__ w2, const float* __restrict__ b2,
                         float* __restrict__ logits) {
    __shared__ float sw1[PERK * CC];
    __shared__ float sb1[PERK];
    __shared__ float sw2[PERK];
    for (int i = threadIdx.x; i < PERK * CC; i += blockDim.x) sw1[i] = w1[i];
    if (threadIdx.x < PERK) { sb1[threadIdx.x] = b1[threadIdx.x]; sw2[threadIdx.x] = w2[threadIdx.x]; }
    __syncthreads();
    int gid = blockIdx.x * blockDim.x + threadIdx.x;   // 8192 threads
    int b = gid >> 10, w = gid & 1023;
    float hid[PERK];
    #pragma unroll
    for (int j = 0; j < PERK; ++j) hid[j] = sb1[j];
    const float* pp = pooled + (size_t)b * CC * NWIN + w;
    for (int c = 0; c < CC; ++c) {
        float pv = pp[(size_t)c * NWIN];
        #pragma unroll
        for (int j = 0; j < PERK; ++j) hid[j] += pv * sw1[j * CC + c];
    }
    float lg = b2[0];
    #pragma unroll
    for (int j = 0; j < PERK; ++j) {
        float hv = hid[j];
        float g = 0.5f * hv * (1.0f + erff(hv * 0.7071067811865476f));
        lg += g * sw2[j];
    }
    logits[gid] = lg;
}

// -------- K3a: softmax over 1024 windows --------
__global__ void k_soft(const float* __restrict__ logits, float* __restrict__ probs) {
    __shared__ float red[NWIN];
    int b = blockIdx.x, t = threadIdx.x;
    float lg = logits[b * NWIN + t];
    red[t] = lg; __syncthreads();
    for (int o = 512; o > 0; o >>= 1) { if (t < o) red[t] = fmaxf(red[t], red[t + o]); __syncthreads(); }
    float mx = red[0]; __syncthreads();
    float e = expf(lg - mx);
    red[t] = e; __syncthreads();
    for (int o = 512; o > 0; o >>= 1) { if (t < o) red[t] += red[t + o]; __syncthreads(); }
    probs[b * NWIN + t] = e / red[0];
}

// -------- K3b: stable descending rank (distributed over 128 blocks) --------
__global__ __launch_bounds__(64) void k_rank2(const float* __restrict__ probs,
        float* __restrict__ rw, int* __restrict__ rank, int* __restrict__ sel) {
    __shared__ __attribute__((aligned(16))) float sp[NWIN];
    int b = blockIdx.x >> 4, slice = blockIdx.x & 15;
    int tid = threadIdx.x;
    for (int i = tid; i < NWIN / 4; i += 64)
        ((float4*)sp)[i] = ((const float4*)(probs + (size_t)b * NWIN))[i];
    __syncthreads();
    int w = slice * 64 + tid;
    float p = sp[w];
    int r = 0;
    for (int j = 0; j < NWIN; j += 4) {
        float4 pj = *(const float4*)&sp[j];
        r += (int)((pj.x > p) || (pj.x == p && (j + 0) < w));
        r += (int)((pj.y > p) || (pj.y == p && (j + 1) < w));
        r += (int)((pj.z > p) || (pj.z == p && (j + 2) < w));
        r += (int)((pj.w > p) || (pj.w == p && (j + 3) < w));
    }
    rank[b * NWIN + w] = r;
    if (r < TOPK) { sel[b * TOPK + r] = w; rw[b * TOPK + r] = p; }
}

// softplus via hardware exp/log
__device__ __forceinline__ float softplus_f(float v) {
    return fmaxf(v, 0.f) + __logf(1.0f + __expf(-fabsf(v)));
}

// chunk t (= scan-window index) -> selected-window id
__device__ __forceinline__ int window_wsel(const int* sel, int b, int k, int t) {
    int qscan = (k >= 2) ? (255 - t) : t;
    int selidx = (k & 1) ? (((qscan & 15) << 4) | (qscan >> 4)) : qscan;
    return sel[b * TOPK + selidx];
}

// gather one selected 7x7 window (49 scan positions x 24 channels) into LDS
__device__ __forceinline__ void gather_win(float (*sxs)[LCP], const float* __restrict__ x,
                                           int b, int k, int wsel, int tid) {
    const float* gbase = x + (((size_t)b * CC + k) * HH + (wsel >> 5) * 7) * HH + (wsel & 31) * 7;
    for (int idx = tid; idx < PERK * 49; idx += 384) {
        int d2 = idx / 49, j = idx - d2 * 49;
        int pix = (k >= 2) ? 48 - j : j;
        int q7 = pix / 7, r7 = pix - q7 * 7;
        int wi = (k & 1) ? r7 : q7;
        int wj = (k & 1) ? q7 : r7;
        sxs[d2][j] = gbase[(size_t)d2 * 4 * HH * HH + wi * HH + wj];
    }
}

// ============ BIG-WS PATH: producer/consumer split ============

// -------- k_prod: gather + FULL 56-row proj + stage dump + phase-1 carries --------
__global__ __launch_bounds__(384, 4) void k_prod(
        const float* __restrict__ x, const float* __restrict__ wcomb,
        const float* __restrict__ dtb, const float* __restrict__ alogs,
        const int* __restrict__ sel, float* __restrict__ stage,
        float* __restrict__ carrP, float* __restrict__ carrS) {
    __shared__ __attribute__((aligned(16))) float sxs[PERK][LCP];
    __shared__ __attribute__((aligned(16))) float sdelta[PERK][LCP];
    __shared__ __attribute__((aligned(16))) float sB[DST][LCP];
    __shared__ __attribute__((aligned(16))) float sC[DST][LCP];
    __shared__ float swt[56 * PERK];
    __shared__ float sbias[PERK];
    int blk = blockIdx.x;               // bk*256 + t
    int t = blk & 255; int bk = blk >> 8; int k = bk & 3; int b = bk >> 2;
    int tid = threadIdx.x;
    gather_win(sxs, x, b, k, window_wsel(sel, b, k, t), tid);
    for (int i = tid; i < 56 * PERK; i += 384) swt[i] = wcomb[k * (56 * PERK) + i];
    if (tid < PERK) sbias[tid] = dtb[k * PERK + tid];
    if (tid < 240) {                    // zero pad columns 49..51
        int r = tid / 3, j = 49 + tid % 3;
        if (r < 24) sxs[r][j] = 0.f;
        else if (r < 48) sdelta[r - 24][j] = 0.f;
        else if (r < 64) sB[r - 48][j] = 0.f;
        else sC[r - 64][j] = 0.f;
    }
    int d = tid >> 4, s = tid & 15;
    float A = -__expf(alogs[(k * PERK + d) * DST + s]);
    __syncthreads();
    // fused projection: rows 0..23 delta (softplus), 24..39 B, 40..55 C
    for (int idx = tid; idx < 56 * NG; idx += 384) {
        int row = idx / NG, g = idx - row * NG; int j = g * 4;
        float bs = (row < PERK) ? sbias[row] : 0.f;
        float ax = bs, ay = bs, az = bs, aw = bs;
        #pragma unroll
        for (int d2 = 0; d2 < PERK; ++d2) {
            float w = swt[row * PERK + d2];
            float4 v = *(const float4*)&sxs[d2][j];
            ax += w * v.x; ay += w * v.y; az += w * v.z; aw += w * v.w;
        }
        float* dst;
        if (row < PERK) {
            ax = softplus_f(ax); ay = softplus_f(ay); az = softplus_f(az); aw = softplus_f(aw);
            dst = &sdelta[row][j];
        } else if (row < PERK + DST) dst = &sB[row - PERK][j];
        else dst = &sC[row - PERK - DST][j];
        if (g < 12) { float4 o = {ax, ay, az, aw}; *(float4*)dst = o; }
        else dst[0] = ax;
    }
    __syncthreads();
    // stage dump: rows 0..23 delta, 24..47 xs, 48..63 B, 64..79 C  ([80][52] per window)
    float* sg = stage + (size_t)blk * WST;
    for (int idx = tid; idx < 80 * NG; idx += 384) {
        int row = idx / NG, g = idx - row * NG;
        const float* src;
        if (row < 24) src = &sdelta[row][g * 4];
        else if (row < 48) src = &sxs[row - 24][g * 4];
        else if (row < 64) src = &sB[row - 48][g * 4];
        else src = &sC[row - 64][g * 4];
        *(float4*)(sg + row * LCP + g * 4) = *(const float4*)src;
    }
    // phase-1 recurrence for carries (reads only; no barrier needed after read-only copy)
    float P = 1.f, S = 0.f;
    for (int g = 0; g < NG; ++g) {
        int j = g * 4;
        float4 dl4 = *(const float4*)&sdelta[d][j];   // pads = 0
        float4 xs4 = *(const float4*)&sxs[d][j];
        float4 B4  = *(const float4*)&sB[s][j];
        float aa;
        aa = __expf(dl4.x * A); S = aa * S + (dl4.x * xs4.x) * B4.x; P *= aa;
        aa = __expf(dl4.y * A); S = aa * S + (dl4.y * xs4.y) * B4.y; P *= aa;
        aa = __expf(dl4.z * A); S = aa * S + (dl4.z * xs4.z) * B4.z; P *= aa;
        aa = __expf(dl4.w * A); S = aa * S + (dl4.w * xs4.w) * B4.w; P *= aa;
    }
    size_t cidx = (size_t)blk * 384 + tid;
    carrP[cidx] = P; carrS[cidx] = S;
}

// -------- k_scan2: recurrence only, operands streamed from stage; y into stage head --------
__global__ __launch_bounds__(384, 4) void k_scan2(
        const float* __restrict__ alogs, const float* __restrict__ dsv,
        const float* __restrict__ hin, float* __restrict__ stage) {
    __shared__ __attribute__((aligned(16))) float sy[PERK][LCP];
    int blk = blockIdx.x;
    int bk = blk >> 8; int k = bk & 3;
    int tid = threadIdx.x;
    int d = tid >> 4, s = tid & 15;
    float A = -__expf(alogs[(k * PERK + d) * DST + s]);
    float Dsr = dsv[k * PERK + d];
    size_t cidx = (size_t)blk * 384 + tid;
    float h = hin[cidx];
    const float* sg = stage + (size_t)blk * WST;
    const float* pdl = sg + d * LCP;
    const float* pxs = sg + (24 + d) * LCP;
    const float* pB  = sg + (48 + s) * LCP;
    const float* pC  = sg + (64 + s) * LCP;
    for (int g = 0; g < NG; ++g) {
        int j = g * 4;
        float4 dl4 = *(const float4*)(pdl + j);   // pads = 0 -> no-op steps
        float4 xs4 = *(const float4*)(pxs + j);
        float4 B4  = *(const float4*)(pB + j);
        float4 C4  = *(const float4*)(pC + j);
        float aa, part;
        aa = __expf(dl4.x * A); h = aa * h + (dl4.x * xs4.x) * B4.x;
        part = h * C4.x;
        ROR_ADD(part, 0x121); ROR_ADD(part, 0x122); ROR_ADD(part, 0x124); ROR_ADD(part, 0x128);
        if (s == 0) sy[d][j] = part + xs4.x * Dsr;
        aa = __expf(dl4.y * A); h = aa * h + (dl4.y * xs4.y) * B4.y;
        part = h * C4.y;
        ROR_ADD(part, 0x121); ROR_ADD(part, 0x122); ROR_ADD(part, 0x124); ROR_ADD(part, 0x128);
        if (s == 0 && j + 1 < 49) sy[d][j + 1] = part + xs4.y * Dsr;
        aa = __expf(dl4.z * A); h = aa * h + (dl4.z * xs4.z) * B4.z;
        part = h * C4.z;
        ROR_ADD(part, 0x121); ROR_ADD(part, 0x122); ROR_ADD(part, 0x124); ROR_ADD(part, 0x128);
        if (s == 0 && j + 2 < 49) sy[d][j + 2] = part + xs4.z * Dsr;
        aa = __expf(dl4.w * A); h = aa * h + (dl4.w * xs4.w) * B4.w;
        part = h * C4.w;
        ROR_ADD(part, 0x121); ROR_ADD(part, 0x122); ROR_ADD(part, 0x124); ROR_ADD(part, 0x128);
        if (s == 0 && j + 3 < 49) sy[d][j + 3] = part + xs4.w * Dsr;
    }
    __syncthreads();   // all stage reads done -> safe to overwrite head with y
    float* yout = stage + (size_t)blk * WST;   // y[j][d], 1176 floats, contiguous
    for (int idx = tid; idx < PERK * 49; idx += 384) {
        int j = idx / PERK, d2 = idx - j * PERK;
        yout[idx] = sy[d2][j];
    }
}

// ============ FALLBACK PATH (round-7 kernels) ============

__global__ __launch_bounds__(384, 4) void k_phase1_fb(
        const float* __restrict__ x, const float* __restrict__ wcomb,
        const float* __restrict__ dtb, const float* __restrict__ alogs,
        const int* __restrict__ sel,
        float* __restrict__ carrP, float* __restrict__ carrS) {
    __shared__ __attribute__((aligned(16))) float sxs[PERK][LCP];
    __shared__ __attribute__((aligned(16))) float sdelta[PERK][LCP];
    __shared__ __attribute__((aligned(16))) float sB[DST][LCP];
    __shared__ float swt[40 * PERK];
    __shared__ float sbias[PERK];
    int blk = blockIdx.x;
    int t = blk & 255; int bk = blk >> 8; int k = bk & 3; int b = bk >> 2;
    int tid = threadIdx.x;
    gather_win(sxs, x, b, k, window_wsel(sel, b, k, t), tid);
    for (int i = tid; i < 40 * PERK; i += 384) swt[i] = wcomb[k * (56 * PERK) + i];
    if (tid < PERK) sbias[tid] = dtb[k * PERK + tid];
    if (tid < 192) {
        int r = tid / 3, j = 49 + tid % 3;
        if (r < 24) sxs[r][j] = 0.f;
        else if (r < 48) sdelta[r - 24][j] = 0.f;
        else sB[r - 48][j] = 0.f;
    }
    int d = tid >> 4, s = tid & 15;
    float A = -__expf(alogs[(k * PERK + d) * DST + s]);
    __syncthreads();
    for (int idx = tid; idx < 40 * NG; idx += 384) {
        int row = idx / NG, g = idx - row * NG; int j = g * 4;
        float bs = (row < PERK) ? sbias[row] : 0.f;
        float ax = bs, ay = bs, az = bs, aw = bs;
        #pragma unroll
        for (int d2 = 0; d2 < PERK; ++d2) {
            float w = swt[row * PERK + d2];
            float4 v = *(const float4*)&sxs[d2][j];
            ax += w * v.x; ay += w * v.y; az += w * v.z; aw += w * v.w;
        }
        float* dst;
        if (row < PERK) {
            ax = softplus_f(ax); ay = softplus_f(ay); az = softplus_f(az); aw = softplus_f(aw);
            dst = &sdelta[row][j];
        } else dst = &sB[row - PERK][j];
        if (g < 12) { float4 o = {ax, ay, az, aw}; *(float4*)dst = o; }
        else dst[0] = ax;
    }
    __syncthreads();
    float P = 1.f, S = 0.f;
    for (int g = 0; g < NG; ++g) {
        int j = g * 4;
        float4 dl4 = *(const float4*)&sdelta[d][j];
        float4 xs4 = *(const float4*)&sxs[d][j];
        float4 B4  = *(const float4*)&sB[s][j];
        float aa;
        aa = __expf(dl4.x * A); S = aa * S + (dl4.x * xs4.x) * B4.x; P *= aa;
        aa = __expf(dl4.y * A); S = aa * S + (dl4.y * xs4.y) * B4.y; P *= aa;
        aa = __expf(dl4.z * A); S = aa * S + (dl4.z * xs4.z) * B4.z; P *= aa;
        aa = __expf(dl4.w * A); S = aa * S + (dl4.w * xs4.w) * B4.w; P *= aa;
    }
    size_t cidx = (size_t)blk * 384 + tid;
    carrP[cidx] = P; carrS[cidx] = S;
}

__global__ __launch_bounds__(384, 4) void k_scan_fb(
        const float* __restrict__ x, const float* __restrict__ wcomb,
        const float* __restrict__ dtb, const float* __restrict__ alogs,
        const float* __restrict__ dsv, const int* __restrict__ sel,
        const float* __restrict__ hin, float* __restrict__ yws) {
    __shared__ __attribute__((aligned(16))) float sxs[PERK][LCP];
    __shared__ __attribute__((aligned(16))) float sdelta[PERK][LCP];
    __shared__ __attribute__((aligned(16))) float sB[DST][LCP];
    __shared__ __attribute__((aligned(16))) float sC[DST][LCP];
    __shared__ float swt[56 * PERK];
    __shared__ float sbias[PERK];
    int blk = blockIdx.x;
    int t = blk & 255; int bk = blk >> 8; int k = bk & 3; int b = bk >> 2;
    int tid = threadIdx.x;
    gather_win(sxs, x, b, k, window_wsel(sel, b, k, t), tid);
    for (int i = tid; i < 56 * PERK; i += 384) swt[i] = wcomb[k * (56 * PERK) + i];
    if (tid < PERK) sbias[tid] = dtb[k * PERK + tid];
    if (tid < 240) {
        int r = tid / 3, j = 49 + tid % 3;
        if (r < 24) sxs[r][j] = 0.f;
        else if (r < 48) sdelta[r - 24][j] = 0.f;
        else if (r < 64) sB[r - 48][j] = 0.f;
        else sC[r - 64][j] = 0.f;
    }
    int d = tid >> 4, s = tid & 15;
    float A = -__expf(alogs[(k * PERK + d) * DST + s]);
    float Dsr = dsv[k * PERK + d];
    size_t cidx = (size_t)blk * 384 + tid;
    float h = hin[cidx];
    __syncthreads();
    for (int idx = tid; idx < 56 * NG; idx += 384) {
        int row = idx / NG, g = idx - row * NG; int j = g * 4;
        float bs = (row < PERK) ? sbias[row] : 0.f;
        float ax = bs, ay = bs, az = bs, aw = bs;
        #pragma unroll
        for (int d2 = 0; d2 < PERK; ++d2) {
            float w = swt[row * PERK + d2];
            float4 v = *(const float4*)&sxs[d2][j];
            ax += w * v.x; ay += w * v.y; az += w * v.z; aw += w * v.w;
        }
        float* dst;
        if (row < PERK) {
            ax = softplus_f(ax); ay = softplus_f(ay); az = softplus_f(az); aw = softplus_f(aw);
            dst = &sdelta[row][j];
        } else if (row < PERK + DST) dst = &sB[row - PERK][j];
        else dst = &sC[row - PERK - DST][j];
        if (g < 12) { float4 o = {ax, ay, az, aw}; *(float4*)dst = o; }
        else dst[0] = ax;
    }
    __syncthreads();
    for (int g = 0; g < NG; ++g) {
        int j = g * 4;
        float4 dl4 = *(const float4*)&sdelta[d][j];
        float4 xs4 = *(const float4*)&sxs[d][j];
        float4 B4  = *(const float4*)&sB[s][j];
        float4 C4  = *(const float4*)&sC[s][j];
        float aa, part;
        aa = __expf(dl4.x * A); h = aa * h + (dl4.x * xs4.x) * B4.x;
        part = h * C4.x;
        ROR_ADD(part, 0x121); ROR_ADD(part, 0x122); ROR_ADD(part, 0x124); ROR_ADD(part, 0x128);
        if (s == 0) sdelta[d][j] = part + xs4.x * Dsr;
        aa = __expf(dl4.y * A); h = aa * h + (dl4.y * xs4.y) * B4.y;
        part = h * C4.y;
        ROR_ADD(part, 0x121); ROR_ADD(part, 0x122); ROR_ADD(part, 0x124); ROR_ADD(part, 0x128);
        if (s == 0 && j + 1 < 49) sdelta[d][j + 1] = part + xs4.y * Dsr;
        aa = __expf(dl4.z * A); h = aa * h + (dl4.z * xs4.z) * B4.z;
        part = h * C4.z;
        ROR_ADD(part, 0x121); ROR_ADD(part, 0x122); ROR_ADD(part, 0x124); ROR_ADD(part, 0x128);
        if (s == 0 && j + 2 < 49) sdelta[d][j + 2] = part + xs4.z * Dsr;
        aa = __expf(dl4.w * A); h = aa * h + (dl4.w * xs4.w) * B4.w;
        part = h * C4.w;
        ROR_ADD(part, 0x121); ROR_ADD(part, 0x122); ROR_ADD(part, 0x124); ROR_ADD(part, 0x128);
        if (s == 0 && j + 3 < 49) sdelta[d][j + 3] = part + xs4.w * Dsr;
    }
    __syncthreads();
    float* ybase = yws + ((size_t)bk * LL + t * 49) * PERK;
    for (int idx = tid; idx < PERK * 49; idx += 384) {
        int j = idx / PERK, d2 = idx - j * PERK;
        ybase[idx] = sdelta[d2][j];
    }
}

// ============ shared epilogue kernels ============

// -------- k_carry: scan across 256 windows (hin may alias carrP: read-before-write) --------
__global__ void k_carry(const float* carrP, const float* carrS, float* hin) {
    int gid = blockIdx.x * blockDim.x + threadIdx.x;   // 12288
    int bk = gid / 384, ds = gid - bk * 384;
    float Hv = 0.f;
    for (int t = 0; t < TCH; ++t) {
        size_t idx = ((size_t)bk * TCH + t) * 384 + ds;
        float pv = carrP[idx], sv = carrS[idx];
        hin[idx] = Hv;
        Hv = pv * Hv + sv;
    }
}

// -------- k_base: out = x*(1+p) unselected, x selected --------
__global__ __launch_bounds__(64) void k_base(const float* __restrict__ x,
        const float* __restrict__ probs, const int* __restrict__ rank,
        float* __restrict__ out) {
    int wr = blockIdx.x % NHW; int bc = blockIdx.x / NHW;
    int b = bc / CC;
    __shared__ float buf[7 * HH];
    __shared__ float fmul[NHW];
    int tid = threadIdx.x;
    const float* xp = x + ((size_t)bc * HH + wr * 7) * HH;
    for (int i = tid; i < 7 * HH; i += 64) buf[i] = xp[i];
    if (tid < NHW) {
        int w = wr * NHW + tid;
        fmul[tid] = (rank[b * NWIN + w] < TOPK) ? 1.0f : (1.0f + probs[b * NWIN + w]);
    }
    __syncthreads();
    int c = bc - b * CC;
    for (int idx = tid; idx < NHW * 49; idx += 64) {
        int wc = idx / 49, r = idx - wc * 49;
        int ri = r / 7, rj = r - ri * 7;
        float v = buf[ri * HH + wc * 7 + rj];
        int w = wr * NHW + wc;
        out[(((size_t)b * NWIN + w) * CC + c) * 49 + r] = v * fmul[wc];
    }
}

// -------- k_yadd: per-selected-window gather of y + contiguous RMW into out --------
// stg!=0: y at ysrc[blk*WST + j*24 + d]; else fallback y at ysrc[(bk*LL+l)*24+d]
__global__ __launch_bounds__(256) void k_yadd(const float* __restrict__ ysrc,
        const int* __restrict__ sel, const float* __restrict__ rw,
        float* __restrict__ out, int stg) {
    __shared__ float ytile[CC * 49];
    int qo = blockIdx.x & 255; int b = blockIdx.x >> 8;
    int wsel = sel[b * TOPK + qo];
    float p = rw[b * TOPK + qo];
    for (int idx = threadIdx.x; idx < CC * 49; idx += 256) {
        int k = idx / 1176; int r1 = idx - k * 1176;
        int u = r1 / 168;   int r2 = r1 - u * 168;
        int wj = r2 / 24;   int d = r2 - wj * 24;
        int rest = qo * 7 + u;
        int b2 = rest & 15; int aw = rest >> 4;
        int wi = aw % 7;    int a = aw / 7;
        int q   = (k & 1) ? (b2 * 16 + a) : (a * 16 + b2);
        int pix = (k & 1) ? (wj * 7 + wi) : (wi * 7 + wj);
        int uu = q * 49 + pix;
        int l = (k >= 2) ? (LL - 1 - uu) : uu;
        int bk = b * 4 + k;
        size_t off;
        if (stg) {
            int t2 = l / 49, jj = l - t2 * 49;
            off = ((size_t)(bk * 256 + t2)) * WST + jj * PERK + d;
        } else {
            off = ((size_t)bk * LL + l) * PERK + d;
        }
        ytile[(k * PERK + d) * 49 + u * 7 + wj] = ysrc[off];
    }
    __syncthreads();
    float* ob = out + ((size_t)(b * NWIN + wsel) * CC) * 49;
    for (int e = threadIdx.x; e < CC * 49; e += 256) ob[e] += p * ytile[e];
}

extern "C" void kernel_launch(void* const* d_in, const int* in_sizes, int n_in,
                              void* d_out, int out_size, void* d_ws, size_t ws_size,
                              hipStream_t stream) {
    const float* x   = (const float*)d_in[0];
    const float* w1  = (const float*)d_in[1];
    const float* b1  = (const float*)d_in[2];
    const float* w2  = (const float*)d_in[3];
    const float* b2  = (const float*)d_in[4];
    const float* xpw = (const float*)d_in[5];
    const float* dtw = (const float*)d_in[6];
    const float* dtb = (const float*)d_in[7];
    const float* alg = (const float*)d_in[8];
    const float* dsv = (const float*)d_in[9];
    float* out = (float*)d_out;
    float* ws  = (float*)d_ws;

    float* pooled = ws + OFF_POOL;
    float* logits = ws + OFF_LOG;
    float* probs  = ws + OFF_PROB;
    float* rwv    = ws + OFF_RW;
    int*   rank   = (int*)(ws + OFF_RANK);
    int*   sel    = (int*)(ws + OFF_SEL);
    float* wcomb  = ws + OFF_WEFF;
    float* cP  = ws + OFF_CP;       // also hin after k_carry
    float* cS  = ws + OFF_CS;

    k_weff  <<<(4 * 56 * PERK + 255) / 256, 256, 0, stream>>>(xpw, dtw, wcomb);
    k_pool  <<<BBATCH * CC, 256, 0, stream>>>(x, pooled);
    k_router<<<BBATCH * NWIN / 256, 256, 0, stream>>>(pooled, w1, b1, w2, b2, logits);
    k_soft  <<<BBATCH, 1024, 0, stream>>>(logits, probs);
    k_rank2 <<<BBATCH * 16, 64, 0, stream>>>(probs, rwv, rank, sel);

    if (ws_size >= NEED_BIG) {
        float* stage = ws + OFF_STG;
        k_prod <<<NBK * TCH, 384, 0, stream>>>(x, wcomb, dtb, alg, sel, stage, cP, cS);
        k_carry<<<48, 256, 0, stream>>>(cP, cS, cP);
        k_base <<<BBATCH * CC * NHW, 64, 0, stream>>>(x, probs, rank, out);
        k_scan2<<<NBK * TCH, 384, 0, stream>>>(alg, dsv, cP, stage);
        k_yadd <<<BBATCH * TOPK, 256, 0, stream>>>(stage, sel, rwv, out, 1);
    } else {
        float* yws = ws + OFF_YWS;
        k_phase1_fb<<<NBK * TCH, 384, 0, stream>>>(x, wcomb, dtb, alg, sel, cP, cS);
        k_carry<<<48, 256, 0, stream>>>(cP, cS, cP);
        k_base <<<BBATCH * CC * NHW, 64, 0, stream>>>(x, probs, rank, out);
        k_scan_fb<<<NBK * TCH, 384, 0, stream>>>(x, wcomb, dtb, alg, dsv, sel, cP, yws);
        k_yadd <<<BBATCH * TOPK, 256, 0, stream>>>(yws, sel, rwv, out, 0);
    }
}

// Round 9
// 524.624 us; speedup vs baseline: 1.1132x; 1.0505x over previous
//
#include <hip/hip_runtime.h>
#include <math.h>

// Problem constants
#define BBATCH 8
#define CC 96
#define HH 224
#define NHW 32            // 224/7 windows per side
#define NWIN 1024
#define TOPK 256
#define PERK 24
#define DST 16
#define DTR 6
#define LL 12544          // 256*49
#define LCP 52            // padded row length (49 used + 3 zero pad)
#define NG 13             // float4 groups per row
#define TCH 256           // one chunk = ONE scan window (49 steps)
#define NBK 32            // B*4 directions
#define XROW 1248         // xs floats per window: 24 x 52
#define WST2 2912         // stage floats per window: 56 rows x 52 (delta,B,C)

// workspace offsets (floats) — total 41,190,656 floats = 164.8 MB (proven available)
#define OFF_POOL 0
#define OFF_LOG  786432
#define OFF_PROB 794624
#define OFF_RW   802816
#define OFF_RANK 804864
#define OFF_SEL  813056
#define OFF_WEFF 815104
#define OFF_CP   820480      // 3,145,728; reused as hin (read-before-write in k_carry)
#define OFF_CS   3966208     // 3,145,728
#define OFF_XSD  7111936     // 10,223,616: xs dense [8192][24][52]
#define OFF_STG  17335552    // 23,855,104: stage [8192][56][52]; y aliased into head

// DPP row_ror:N add — 16-lane full-sum reduction on the VALU pipe (not DS)
#define ROR_ADD(v, CTRL) \
    v += __int_as_float(__builtin_amdgcn_update_dpp(0, __float_as_int(v), CTRL, 0xf, 0xf, true))

// -------- K1: window pooling: pooledT[b][c][w] --------
__global__ void k_pool(const float* __restrict__ x, float* __restrict__ pooled) {
    int bc = blockIdx.x;                 // b*96+c
    const float* xp = x + (size_t)bc * HH * HH;
    float* pp = pooled + (size_t)bc * NWIN;
    for (int w = threadIdx.x; w < NWIN; w += blockDim.x) {
        int wr = w >> 5, wc = w & 31;
        const float* base = xp + (wr * 7) * HH + wc * 7;
        float s = 0.f;
        #pragma unroll
        for (int i = 0; i < 7; ++i) {
            #pragma unroll
            for (int j = 0; j < 7; ++j) s += base[i * HH + j];
        }
        pp[w] = s * (1.0f / 49.0f);
    }
}

// -------- k_route: weff + router MLP + softmax + stable rank, one kernel, 8 blocks --------
__global__ __launch_bounds__(1024) void k_route(
        const float* __restrict__ pooled,
        const float* __restrict__ w1, const float* __restrict__ b1,
        const float* __restrict__ w2, const float* __restrict__ b2,
        const float* __restrict__ xpw, const float* __restrict__ dtw,
        float* __restrict__ wcomb, float* __restrict__ probs,
        float* __restrict__ rw, int* __restrict__ rank, int* __restrict__ sel) {
    __shared__ float sw1[PERK * CC];
    __shared__ float sb1[PERK];
    __shared__ float sw2[PERK];
    __shared__ __attribute__((aligned(16))) float sp[NWIN];
    __shared__ float red[NWIN];
    int b = blockIdx.x, t = threadIdx.x;
    // ---- weff slice (independent; wcomb used only by later kernels) ----
    for (int i = b * 1024 + t; i < 4 * 56 * PERK; i += 8 * 1024) {
        int k = i / (56 * PERK), rem = i - k * (56 * PERK);
        int row = rem / PERK, c = rem - row * PERK;
        float v;
        if (row < PERK) {
            v = 0.f;
            #pragma unroll
            for (int r = 0; r < DTR; ++r)
                v += dtw[(k * PERK + row) * DTR + r] * xpw[(k * 38 + r) * PERK + c];
        } else {
            v = xpw[(k * 38 + (row - PERK + DTR)) * PERK + c];
        }
        wcomb[i] = v;
    }
    // ---- router ----
    for (int i = t; i < PERK * CC; i += 1024) sw1[i] = w1[i];
    if (t < PERK) { sb1[t] = b1[t]; sw2[t] = w2[t]; }
    __syncthreads();
    float hid[PERK];
    #pragma unroll
    for (int j = 0; j < PERK; ++j) hid[j] = sb1[j];
    const float* pp = pooled + (size_t)b * CC * NWIN + t;
    for (int c = 0; c < CC; ++c) {
        float pv = pp[(size_t)c * NWIN];
        #pragma unroll
        for (int j = 0; j < PERK; ++j) hid[j] += pv * sw1[j * CC + c];
    }
    float lg = b2[0];
    #pragma unroll
    for (int j = 0; j < PERK; ++j) {
        float hv = hid[j];
        float g = 0.5f * hv * (1.0f + erff(hv * 0.7071067811865476f));
        lg += g * sw2[j];
    }
    // ---- softmax ----
    red[t] = lg; __syncthreads();
    for (int o = 512; o > 0; o >>= 1) { if (t < o) red[t] = fmaxf(red[t], red[t + o]); __syncthreads(); }
    float mx = red[0]; __syncthreads();
    float e = expf(lg - mx);
    red[t] = e; __syncthreads();
    for (int o = 512; o > 0; o >>= 1) { if (t < o) red[t] += red[t + o]; __syncthreads(); }
    float p = e / red[0];
    probs[b * NWIN + t] = p;
    sp[t] = p;
    __syncthreads();
    // ---- stable descending rank (jax.lax.top_k semantics) ----
    int r = 0;
    for (int j = 0; j < NWIN; j += 4) {
        float4 pj = *(const float4*)&sp[j];
        r += (int)((pj.x > p) || (pj.x == p && (j + 0) < t));
        r += (int)((pj.y > p) || (pj.y == p && (j + 1) < t));
        r += (int)((pj.z > p) || (pj.z == p && (j + 2) < t));
        r += (int)((pj.w > p) || (pj.w == p && (j + 3) < t));
    }
    rank[b * NWIN + t] = r;
    if (r < TOPK) { sel[b * TOPK + r] = t; rw[b * TOPK + r] = p; }
}

// softplus via hardware exp/log
__device__ __forceinline__ float softplus_f(float v) {
    return fmaxf(v, 0.f) + __logf(1.0f + __expf(-fabsf(v)));
}

// chunk t (= scan-window index) -> selected-window id
__device__ __forceinline__ int window_wsel(const int* sel, int b, int k, int t) {
    int qscan = (k >= 2) ? (255 - t) : t;
    int selidx = (k & 1) ? (((qscan & 15) << 4) | (qscan >> 4)) : qscan;
    return sel[b * TOPK + selidx];
}

// -------- k_gather: scattered x -> dense xs [blk][24][52], barrier-free streaming --------
__global__ __launch_bounds__(256) void k_gather(const float* __restrict__ x,
        const int* __restrict__ sel, float* __restrict__ xsd) {
    const int total = NBK * TCH * XROW;   // 10,223,616
    for (int e = blockIdx.x * 256 + threadIdx.x; e < total; e += gridDim.x * 256) {
        int blk = e / XROW;
        int rem = e - blk * XROW;
        int d2 = rem / LCP, j = rem - d2 * LCP;
        float v = 0.f;
        if (j < 49) {
            int t = blk & 255, bk = blk >> 8, k = bk & 3, b = bk >> 2;
            int wsel = window_wsel(sel, b, k, t);
            int pix = (k >= 2) ? 48 - j : j;
            int q7 = pix / 7, r7 = pix - q7 * 7;
            int wi = (k & 1) ? r7 : q7;
            int wj = (k & 1) ? q7 : r7;
            v = x[(((size_t)b * CC + 4 * d2 + k) * HH + (wsel >> 5) * 7 + wi) * HH
                  + (wsel & 31) * 7 + wj];
        }
        xsd[e] = v;
    }
}

// -------- k_prodD: dense xs -> proj (delta,B,C) staged + phase-1 carries --------
__global__ __launch_bounds__(384, 4) void k_prodD(
        const float* __restrict__ xsd, const float* __restrict__ wcomb,
        const float* __restrict__ dtb, const float* __restrict__ alogs,
        float* __restrict__ stage, float* __restrict__ carrP, float* __restrict__ carrS) {
    __shared__ __attribute__((aligned(16))) float sxs[PERK][LCP];
    __shared__ __attribute__((aligned(16))) float sprj[56][LCP];  // 0..23 delta, 24..39 B, 40..55 C
    __shared__ float swt[56 * PERK];
    __shared__ float sbias[PERK];
    int blk = blockIdx.x;
    int bk = blk >> 8; int k = bk & 3;
    int tid = threadIdx.x;
    // dense coalesced xs load (pads already zero)
    const float4* xin = (const float4*)(xsd + (size_t)blk * XROW);
    for (int i = tid; i < XROW / 4; i += 384) ((float4*)sxs)[i] = xin[i];
    for (int i = tid; i < 56 * PERK; i += 384) swt[i] = wcomb[k * (56 * PERK) + i];
    if (tid < PERK) sbias[tid] = dtb[k * PERK + tid];
    if (tid < 168) {                    // zero pad columns 49..51 of sprj
        int r = tid / 3, j = 49 + tid % 3;
        sprj[r][j] = 0.f;
    }
    int d = tid >> 4, s = tid & 15;
    float A = -__expf(alogs[(k * PERK + d) * DST + s]);
    __syncthreads();
    // fused projection: rows 0..23 softplus(Weff*xs+bias), 24..39 B, 40..55 C
    for (int idx = tid; idx < 56 * NG; idx += 384) {
        int row = idx / NG, g = idx - row * NG; int j = g * 4;
        float bs = (row < PERK) ? sbias[row] : 0.f;
        float ax = bs, ay = bs, az = bs, aw = bs;
        #pragma unroll
        for (int d2 = 0; d2 < PERK; ++d2) {
            float w = swt[row * PERK + d2];
            float4 v = *(const float4*)&sxs[d2][j];
            ax += w * v.x; ay += w * v.y; az += w * v.z; aw += w * v.w;
        }
        if (row < PERK) {
            ax = softplus_f(ax); ay = softplus_f(ay); az = softplus_f(az); aw = softplus_f(aw);
        }
        float* dst = &sprj[row][j];
        if (g < 12) { float4 o = {ax, ay, az, aw}; *(float4*)dst = o; }
        else dst[0] = ax;
    }
    __syncthreads();
    // stage dump (coalesced float4) + phase-1 recurrence
    float4* sg = (float4*)(stage + (size_t)blk * WST2);
    const float4* sp4 = (const float4*)&sprj[0][0];
    for (int i = tid; i < WST2 / 4; i += 384) sg[i] = sp4[i];
    float P = 1.f, S = 0.f;
    for (int g = 0; g < NG; ++g) {
        int j = g * 4;
        float4 dl4 = *(const float4*)&sprj[d][j];        // pads = 0
        float4 xs4 = *(const float4*)&sxs[d][j];
        float4 B4  = *(const float4*)&sprj[24 + s][j];
        float aa;
        aa = __expf(dl4.x * A); S = aa * S + (dl4.x * xs4.x) * B4.x; P *= aa;
        aa = __expf(dl4.y * A); S = aa * S + (dl4.y * xs4.y) * B4.y; P *= aa;
        aa = __expf(dl4.z * A); S = aa * S + (dl4.z * xs4.z) * B4.z; P *= aa;
        aa = __expf(dl4.w * A); S = aa * S + (dl4.w * xs4.w) * B4.w; P *= aa;
    }
    size_t cidx = (size_t)blk * 384 + tid;
    carrP[cidx] = P; carrS[cidx] = S;
}

// -------- k_carry: scan across 256 windows (hin may alias carrP: read-before-write) --------
__global__ void k_carry(const float* carrP, const float* carrS, float* hin) {
    int gid = blockIdx.x * blockDim.x + threadIdx.x;   // 12288
    int bk = gid / 384, ds = gid - bk * 384;
    float Hv = 0.f;
    for (int t = 0; t < TCH; ++t) {
        size_t idx = ((size_t)bk * TCH + t) * 384 + ds;
        float pv = carrP[idx], sv = carrS[idx];
        hin[idx] = Hv;
        Hv = pv * Hv + sv;
    }
}

// -------- k_base: out = x*(1+p) unselected, x selected --------
__global__ __launch_bounds__(64) void k_base(const float* __restrict__ x,
        const float* __restrict__ probs, const int* __restrict__ rank,
        float* __restrict__ out) {
    int wr = blockIdx.x % NHW; int bc = blockIdx.x / NHW;
    int b = bc / CC;
    __shared__ float buf[7 * HH];
    __shared__ float fmul[NHW];
    int tid = threadIdx.x;
    const float* xp = x + ((size_t)bc * HH + wr * 7) * HH;
    for (int i = tid; i < 7 * HH; i += 64) buf[i] = xp[i];
    if (tid < NHW) {
        int w = wr * NHW + tid;
        fmul[tid] = (rank[b * NWIN + w] < TOPK) ? 1.0f : (1.0f + probs[b * NWIN + w]);
    }
    __syncthreads();
    int c = bc - b * CC;
    for (int idx = tid; idx < NHW * 49; idx += 64) {
        int wc = idx / 49, r = idx - wc * 49;
        int ri = r / 7, rj = r - ri * 7;
        float v = buf[ri * HH + wc * 7 + rj];
        int w = wr * NHW + wc;
        out[(((size_t)b * NWIN + w) * CC + c) * 49 + r] = v * fmul[wc];
    }
}

// -------- k_scan2: recurrence only; streams xsd + stage; y into stage head --------
__global__ __launch_bounds__(384, 4) void k_scan2(
        const float* __restrict__ alogs, const float* __restrict__ dsv,
        const float* __restrict__ hin, const float* __restrict__ xsd,
        float* __restrict__ stage) {
    __shared__ __attribute__((aligned(16))) float sy[PERK][LCP];
    int blk = blockIdx.x;
    int bk = blk >> 8; int k = bk & 3;
    int tid = threadIdx.x;
    int d = tid >> 4, s = tid & 15;
    float A = -__expf(alogs[(k * PERK + d) * DST + s]);
    float Dsr = dsv[k * PERK + d];
    size_t cidx = (size_t)blk * 384 + tid;
    float h = hin[cidx];
    const float* sg = stage + (size_t)blk * WST2;
    const float* pdl = sg + d * LCP;
    const float* pB  = sg + (24 + s) * LCP;
    const float* pC  = sg + (40 + s) * LCP;
    const float* pxs = xsd + (size_t)blk * XROW + d * LCP;
    for (int g = 0; g < NG; ++g) {
        int j = g * 4;
        float4 dl4 = *(const float4*)(pdl + j);   // pads = 0 -> no-op steps
        float4 xs4 = *(const float4*)(pxs + j);
        float4 B4  = *(const float4*)(pB + j);
        float4 C4  = *(const float4*)(pC + j);
        float aa, part;
        aa = __expf(dl4.x * A); h = aa * h + (dl4.x * xs4.x) * B4.x;
        part = h * C4.x;
        ROR_ADD(part, 0x121); ROR_ADD(part, 0x122); ROR_ADD(part, 0x124); ROR_ADD(part, 0x128);
        if (s == 0) sy[d][j] = part + xs4.x * Dsr;
        aa = __expf(dl4.y * A); h = aa * h + (dl4.y * xs4.y) * B4.y;
        part = h * C4.y;
        ROR_ADD(part, 0x121); ROR_ADD(part, 0x122); ROR_ADD(part, 0x124); ROR_ADD(part, 0x128);
        if (s == 0 && j + 1 < 49) sy[d][j + 1] = part + xs4.y * Dsr;
        aa = __expf(dl4.z * A); h = aa * h + (dl4.z * xs4.z) * B4.z;
        part = h * C4.z;
        ROR_ADD(part, 0x121); ROR_ADD(part, 0x122); ROR_ADD(part, 0x124); ROR_ADD(part, 0x128);
        if (s == 0 && j + 2 < 49) sy[d][j + 2] = part + xs4.z * Dsr;
        aa = __expf(dl4.w * A); h = aa * h + (dl4.w * xs4.w) * B4.w;
        part = h * C4.w;
        ROR_ADD(part, 0x121); ROR_ADD(part, 0x122); ROR_ADD(part, 0x124); ROR_ADD(part, 0x128);
        if (s == 0 && j + 3 < 49) sy[d][j + 3] = part + xs4.w * Dsr;
    }
    __syncthreads();   // all stage reads done -> safe to overwrite head with y
    float* yout = stage + (size_t)blk * WST2;   // y[j][d], 1176 floats, contiguous
    for (int idx = tid; idx < PERK * 49; idx += 384) {
        int j = idx / PERK, d2 = idx - j * PERK;
        yout[idx] = sy[d2][j];
    }
}

// -------- k_yadd: per-selected-window gather of y + contiguous RMW into out --------
__global__ __launch_bounds__(256) void k_yadd(const float* __restrict__ stage,
        const int* __restrict__ sel, const float* __restrict__ rw,
        float* __restrict__ out) {
    __shared__ float ytile[CC * 49];
    int qo = blockIdx.x & 255; int b = blockIdx.x >> 8;
    int wsel = sel[b * TOPK + qo];
    float p = rw[b * TOPK + qo];
    for (int idx = threadIdx.x; idx < CC * 49; idx += 256) {
        int k = idx / 1176; int r1 = idx - k * 1176;
        int u = r1 / 168;   int r2 = r1 - u * 168;
        int wj = r2 / 24;   int d = r2 - wj * 24;
        int rest = qo * 7 + u;
        int b2 = rest & 15; int aw = rest >> 4;
        int wi = aw % 7;    int a = aw / 7;
        int q   = (k & 1) ? (b2 * 16 + a) : (a * 16 + b2);
        int pix = (k & 1) ? (wj * 7 + wi) : (wi * 7 + wj);
        int uu = q * 49 + pix;
        int l = (k >= 2) ? (LL - 1 - uu) : uu;
        int bk = b * 4 + k;
        int t2 = l / 49, jj = l - t2 * 49;
        ytile[(k * PERK + d) * 49 + u * 7 + wj] =
            stage[((size_t)(bk * 256 + t2)) * WST2 + jj * PERK + d];
    }
    __syncthreads();
    float* ob = out + ((size_t)(b * NWIN + wsel) * CC) * 49;
    for (int e = threadIdx.x; e < CC * 49; e += 256) ob[e] += p * ytile[e];
}

extern "C" void kernel_launch(void* const* d_in, const int* in_sizes, int n_in,
                              void* d_out, int out_size, void* d_ws, size_t ws_size,
                              hipStream_t stream) {
    const float* x   = (const float*)d_in[0];
    const float* w1  = (const float*)d_in[1];
    const float* b1  = (const float*)d_in[2];
    const float* w2  = (const float*)d_in[3];
    const float* b2  = (const float*)d_in[4];
    const float* xpw = (const float*)d_in[5];
    const float* dtw = (const float*)d_in[6];
    const float* dtb = (const float*)d_in[7];
    const float* alg = (const float*)d_in[8];
    const float* dsv = (const float*)d_in[9];
    float* out = (float*)d_out;
    float* ws  = (float*)d_ws;

    float* pooled = ws + OFF_POOL;
    float* probs  = ws + OFF_PROB;
    float* rwv    = ws + OFF_RW;
    int*   rank   = (int*)(ws + OFF_RANK);
    int*   sel    = (int*)(ws + OFF_SEL);
    float* wcomb  = ws + OFF_WEFF;
    float* cP  = ws + OFF_CP;       // also hin after k_carry
    float* cS  = ws + OFF_CS;
    float* xsd = ws + OFF_XSD;
    float* stage = ws + OFF_STG;

    k_pool  <<<BBATCH * CC, 256, 0, stream>>>(x, pooled);
    k_route <<<BBATCH, 1024, 0, stream>>>(pooled, w1, b1, w2, b2, xpw, dtw,
                                          wcomb, probs, rwv, rank, sel);
    k_gather<<<2048, 256, 0, stream>>>(x, sel, xsd);
    k_prodD <<<NBK * TCH, 384, 0, stream>>>(xsd, wcomb, dtb, alg, stage, cP, cS);
    k_carry <<<48, 256, 0, stream>>>(cP, cS, cP);     // hin aliases cP (read-before-write)
    k_base  <<<BBATCH * CC * NHW, 64, 0, stream>>>(x, probs, rank, out);
    k_scan2 <<<NBK * TCH, 384, 0, stream>>>(alg, dsv, cP, xsd, stage);
    k_yadd  <<<BBATCH * TOPK, 256, 0, stream>>>(stage, sel, rwv, out);
}

// Round 10
// 504.984 us; speedup vs baseline: 1.1565x; 1.0389x over previous
//
#include <hip/hip_runtime.h>
#include <math.h>

// Problem constants
#define BBATCH 8
#define CC 96
#define HH 224
#define NHW 32            // 224/7 windows per side
#define NWIN 1024
#define TOPK 256
#define PERK 24
#define DST 16
#define DTR 6
#define LL 12544          // 256*49
#define LCP 52            // padded row length (49 used + 3 zero pad)
#define NG 13             // float4 groups per row
#define TCH 256           // one chunk = ONE scan window (49 steps)
#define NBK 32            // B*4 directions
#define XROW 1248         // xs floats per window: 24 x 52
#define WST2 2912         // stage floats per window: 56 rows x 52 (delta,B,C)

// workspace offsets (floats) — total 41,190,656 floats = 164.8 MB (proven available)
#define OFF_POOL 0
#define OFF_PROB 794624
#define OFF_RW   802816
#define OFF_RANK 804864
#define OFF_SEL  813056
#define OFF_WEFF 815104
#define OFF_CP   820480      // 3,145,728; reused as hin (read-before-write in k_carry)
#define OFF_CS   3966208     // 3,145,728
#define OFF_XSD  7111936     // 10,223,616: xs dense [8192][24][52]
#define OFF_STG  17335552    // 23,855,104: stage [8192][56][52]; y aliased into head

// DPP row_ror:N add — 16-lane full-sum reduction on the VALU pipe (not DS)
#define ROR_ADD(v, CTRL) \
    v += __int_as_float(__builtin_amdgcn_update_dpp(0, __float_as_int(v), CTRL, 0xf, 0xf, true))

// -------- K1: window pooling: pooledT[b][c][w] --------
__global__ void k_pool(const float* __restrict__ x, float* __restrict__ pooled) {
    int bc = blockIdx.x;                 // b*96+c
    const float* xp = x + (size_t)bc * HH * HH;
    float* pp = pooled + (size_t)bc * NWIN;
    for (int w = threadIdx.x; w < NWIN; w += blockDim.x) {
        int wr = w >> 5, wc = w & 31;
        const float* base = xp + (wr * 7) * HH + wc * 7;
        float s = 0.f;
        #pragma unroll
        for (int i = 0; i < 7; ++i) {
            #pragma unroll
            for (int j = 0; j < 7; ++j) s += base[i * HH + j];
        }
        pp[w] = s * (1.0f / 49.0f);
    }
}

// -------- k_route: weff + router MLP + softmax (rank moved to k_rank2) --------
__global__ __launch_bounds__(1024) void k_route(
        const float* __restrict__ pooled,
        const float* __restrict__ w1, const float* __restrict__ b1,
        const float* __restrict__ w2, const float* __restrict__ b2,
        const float* __restrict__ xpw, const float* __restrict__ dtw,
        float* __restrict__ wcomb, float* __restrict__ probs) {
    __shared__ float sw1[PERK * CC];
    __shared__ float sb1[PERK];
    __shared__ float sw2[PERK];
    __shared__ float red[NWIN];
    int b = blockIdx.x, t = threadIdx.x;
    // ---- weff slice ----
    for (int i = b * 1024 + t; i < 4 * 56 * PERK; i += 8 * 1024) {
        int k = i / (56 * PERK), rem = i - k * (56 * PERK);
        int row = rem / PERK, c = rem - row * PERK;
        float v;
        if (row < PERK) {
            v = 0.f;
            #pragma unroll
            for (int r = 0; r < DTR; ++r)
                v += dtw[(k * PERK + row) * DTR + r] * xpw[(k * 38 + r) * PERK + c];
        } else {
            v = xpw[(k * 38 + (row - PERK + DTR)) * PERK + c];
        }
        wcomb[i] = v;
    }
    // ---- router ----
    for (int i = t; i < PERK * CC; i += 1024) sw1[i] = w1[i];
    if (t < PERK) { sb1[t] = b1[t]; sw2[t] = w2[t]; }
    __syncthreads();
    float hid[PERK];
    #pragma unroll
    for (int j = 0; j < PERK; ++j) hid[j] = sb1[j];
    const float* pp = pooled + (size_t)b * CC * NWIN + t;
    for (int c = 0; c < CC; ++c) {
        float pv = pp[(size_t)c * NWIN];
        #pragma unroll
        for (int j = 0; j < PERK; ++j) hid[j] += pv * sw1[j * CC + c];
    }
    float lg = b2[0];
    #pragma unroll
    for (int j = 0; j < PERK; ++j) {
        float hv = hid[j];
        float g = 0.5f * hv * (1.0f + erff(hv * 0.7071067811865476f));
        lg += g * sw2[j];
    }
    // ---- softmax ----
    red[t] = lg; __syncthreads();
    for (int o = 512; o > 0; o >>= 1) { if (t < o) red[t] = fmaxf(red[t], red[t + o]); __syncthreads(); }
    float mx = red[0]; __syncthreads();
    float e = expf(lg - mx);
    red[t] = e; __syncthreads();
    for (int o = 512; o > 0; o >>= 1) { if (t < o) red[t] += red[t + o]; __syncthreads(); }
    probs[b * NWIN + t] = e / red[0];
}

// -------- k_rank2: stable descending rank (128 blocks) --------
__global__ __launch_bounds__(64) void k_rank2(const float* __restrict__ probs,
        float* __restrict__ rw, int* __restrict__ rank, int* __restrict__ sel) {
    __shared__ __attribute__((aligned(16))) float sp[NWIN];
    int b = blockIdx.x >> 4, slice = blockIdx.x & 15;
    int tid = threadIdx.x;
    for (int i = tid; i < NWIN / 4; i += 64)
        ((float4*)sp)[i] = ((const float4*)(probs + (size_t)b * NWIN))[i];
    __syncthreads();
    int w = slice * 64 + tid;
    float p = sp[w];
    int r = 0;
    for (int j = 0; j < NWIN; j += 4) {
        float4 pj = *(const float4*)&sp[j];
        r += (int)((pj.x > p) || (pj.x == p && (j + 0) < w));
        r += (int)((pj.y > p) || (pj.y == p && (j + 1) < w));
        r += (int)((pj.z > p) || (pj.z == p && (j + 2) < w));
        r += (int)((pj.w > p) || (pj.w == p && (j + 3) < w));
    }
    rank[b * NWIN + w] = r;
    if (r < TOPK) { sel[b * TOPK + r] = w; rw[b * TOPK + r] = p; }
}

// softplus via hardware exp/log
__device__ __forceinline__ float softplus_f(float v) {
    return fmaxf(v, 0.f) + __logf(1.0f + __expf(-fabsf(v)));
}

// chunk t (= scan-window index) -> selected-window id
__device__ __forceinline__ int window_wsel(const int* sel, int b, int k, int t) {
    int qscan = (k >= 2) ? (255 - t) : t;
    int selidx = (k & 1) ? (((qscan & 15) << 4) | (qscan >> 4)) : qscan;
    return sel[b * TOPK + selidx];
}

// -------- k_gather: scattered x -> dense xs [blk][24][52], barrier-free streaming --------
__global__ __launch_bounds__(256) void k_gather(const float* __restrict__ x,
        const int* __restrict__ sel, float* __restrict__ xsd) {
    const int total = NBK * TCH * XROW;   // 10,223,616
    for (int e = blockIdx.x * 256 + threadIdx.x; e < total; e += gridDim.x * 256) {
        int blk = e / XROW;
        int rem = e - blk * XROW;
        int d2 = rem / LCP, j = rem - d2 * LCP;
        float v = 0.f;
        if (j < 49) {
            int t = blk & 255, bk = blk >> 8, k = bk & 3, b = bk >> 2;
            int wsel = window_wsel(sel, b, k, t);
            int pix = (k >= 2) ? 48 - j : j;
            int q7 = pix / 7, r7 = pix - q7 * 7;
            int wi = (k & 1) ? r7 : q7;
            int wj = (k & 1) ? q7 : r7;
            v = x[(((size_t)b * CC + 4 * d2 + k) * HH + (wsel >> 5) * 7 + wi) * HH
                  + (wsel & 31) * 7 + wj];
        }
        xsd[e] = v;
    }
}

// -------- k_prodD: dense xs -> proj (delta,B,C) staged + phase-1 carries --------
__global__ __launch_bounds__(384, 4) void k_prodD(
        const float* __restrict__ xsd, const float* __restrict__ wcomb,
        const float* __restrict__ dtb, const float* __restrict__ alogs,
        float* __restrict__ stage, float* __restrict__ carrP, float* __restrict__ carrS) {
    __shared__ __attribute__((aligned(16))) float sxs[PERK][LCP];
    __shared__ __attribute__((aligned(16))) float sprj[56][LCP];  // 0..23 delta, 24..39 B, 40..55 C
    __shared__ float swt[56 * PERK];
    __shared__ float sbias[PERK];
    int blk = blockIdx.x;
    int bk = blk >> 8; int k = bk & 3;
    int tid = threadIdx.x;
    const float4* xin = (const float4*)(xsd + (size_t)blk * XROW);
    for (int i = tid; i < XROW / 4; i += 384) ((float4*)sxs)[i] = xin[i];
    for (int i = tid; i < 56 * PERK; i += 384) swt[i] = wcomb[k * (56 * PERK) + i];
    if (tid < PERK) sbias[tid] = dtb[k * PERK + tid];
    if (tid < 168) {                    // zero pad columns 49..51 of sprj
        int r = tid / 3, j = 49 + tid % 3;
        sprj[r][j] = 0.f;
    }
    int d = tid >> 4, s = tid & 15;
    float A = -__expf(alogs[(k * PERK + d) * DST + s]);
    __syncthreads();
    for (int idx = tid; idx < 56 * NG; idx += 384) {
        int row = idx / NG, g = idx - row * NG; int j = g * 4;
        float bs = (row < PERK) ? sbias[row] : 0.f;
        float ax = bs, ay = bs, az = bs, aw = bs;
        #pragma unroll
        for (int d2 = 0; d2 < PERK; ++d2) {
            float w = swt[row * PERK + d2];
            float4 v = *(const float4*)&sxs[d2][j];
            ax += w * v.x; ay += w * v.y; az += w * v.z; aw += w * v.w;
        }
        if (row < PERK) {
            ax = softplus_f(ax); ay = softplus_f(ay); az = softplus_f(az); aw = softplus_f(aw);
        }
        float* dst = &sprj[row][j];
        if (g < 12) { float4 o = {ax, ay, az, aw}; *(float4*)dst = o; }
        else dst[0] = ax;
    }
    __syncthreads();
    float4* sg = (float4*)(stage + (size_t)blk * WST2);
    const float4* sp4 = (const float4*)&sprj[0][0];
    for (int i = tid; i < WST2 / 4; i += 384) sg[i] = sp4[i];
    float P = 1.f, S = 0.f;
    for (int g = 0; g < NG; ++g) {
        int j = g * 4;
        float4 dl4 = *(const float4*)&sprj[d][j];        // pads = 0
        float4 xs4 = *(const float4*)&sxs[d][j];
        float4 B4  = *(const float4*)&sprj[24 + s][j];
        float aa;
        aa = __expf(dl4.x * A); S = aa * S + (dl4.x * xs4.x) * B4.x; P *= aa;
        aa = __expf(dl4.y * A); S = aa * S + (dl4.y * xs4.y) * B4.y; P *= aa;
        aa = __expf(dl4.z * A); S = aa * S + (dl4.z * xs4.z) * B4.z; P *= aa;
        aa = __expf(dl4.w * A); S = aa * S + (dl4.w * xs4.w) * B4.w; P *= aa;
    }
    size_t cidx = (size_t)blk * 384 + tid;
    carrP[cidx] = P; carrS[cidx] = S;
}

// -------- k_carry: scan across 256 windows (hin may alias carrP: read-before-write) --------
__global__ void k_carry(const float* carrP, const float* carrS, float* hin) {
    int gid = blockIdx.x * blockDim.x + threadIdx.x;   // 12288
    int bk = gid / 384, ds = gid - bk * 384;
    float Hv = 0.f;
    for (int t = 0; t < TCH; ++t) {
        size_t idx = ((size_t)bk * TCH + t) * 384 + ds;
        float pv = carrP[idx], sv = carrS[idx];
        hin[idx] = Hv;
        Hv = pv * Hv + sv;
    }
}

// -------- k_base: out = x*(1+p) for UNSELECTED windows only (selected written by k_yadd) --------
__global__ __launch_bounds__(64) void k_base(const float* __restrict__ x,
        const float* __restrict__ probs, const int* __restrict__ rank,
        float* __restrict__ out) {
    int wr = blockIdx.x % NHW; int bc = blockIdx.x / NHW;
    int b = bc / CC;
    __shared__ float buf[7 * HH];
    __shared__ float fmul[NHW];
    __shared__ int   fsel[NHW];
    int tid = threadIdx.x;
    const float* xp = x + ((size_t)bc * HH + wr * 7) * HH;
    for (int i = tid; i < 7 * HH; i += 64) buf[i] = xp[i];
    if (tid < NHW) {
        int w = wr * NHW + tid;
        fsel[tid] = (rank[b * NWIN + w] < TOPK);
        fmul[tid] = 1.0f + probs[b * NWIN + w];
    }
    __syncthreads();
    int c = bc - b * CC;
    for (int idx = tid; idx < NHW * 49; idx += 64) {
        int wc = idx / 49, r = idx - wc * 49;
        if (fsel[wc]) continue;
        int ri = r / 7, rj = r - ri * 7;
        float v = buf[ri * HH + wc * 7 + rj];
        int w = wr * NHW + wc;
        out[(((size_t)b * NWIN + w) * CC + c) * 49 + r] = v * fmul[wc];
    }
}

// -------- k_scan2: recurrence only; depth-2 prefetch pipeline; y into stage head --------
__global__ __launch_bounds__(384, 4) void k_scan2(
        const float* __restrict__ alogs, const float* __restrict__ dsv,
        const float* __restrict__ hin, const float* __restrict__ xsd,
        float* __restrict__ stage) {
    __shared__ __attribute__((aligned(16))) float sy[PERK][LCP];
    int blk = blockIdx.x;
    int bk = blk >> 8; int k = bk & 3;
    int tid = threadIdx.x;
    int d = tid >> 4, s = tid & 15;
    float A = -__expf(alogs[(k * PERK + d) * DST + s]);
    float Dsr = dsv[k * PERK + d];
    size_t cidx = (size_t)blk * 384 + tid;
    float h = hin[cidx];
    const float* sg = stage + (size_t)blk * WST2;
    const float* pdl = sg + d * LCP;
    const float* pB  = sg + (24 + s) * LCP;
    const float* pC  = sg + (40 + s) * LCP;
    const float* pxs = xsd + (size_t)blk * XROW + d * LCP;
    // depth-2 software pipeline: groups g (current), g+1 (staged), g+2 (prefetching)
    float4 dlC = *(const float4*)(pdl);     float4 xsC = *(const float4*)(pxs);
    float4 BC_ = *(const float4*)(pB);      float4 CC_ = *(const float4*)(pC);
    float4 dlN = *(const float4*)(pdl + 4); float4 xsN = *(const float4*)(pxs + 4);
    float4 BN_ = *(const float4*)(pB + 4);  float4 CN_ = *(const float4*)(pC + 4);
    for (int g = 0; g < NG; ++g) {
        float4 dl4 = dlC, xs4 = xsC, B4 = BC_, C4 = CC_;
        dlC = dlN; xsC = xsN; BC_ = BN_; CC_ = CN_;
        if (g + 2 < NG) {
            int jn = (g + 2) * 4;
            dlN = *(const float4*)(pdl + jn); xsN = *(const float4*)(pxs + jn);
            BN_ = *(const float4*)(pB + jn);  CN_ = *(const float4*)(pC + jn);
        }
        int j = g * 4;
        float aa, part;
        aa = __expf(dl4.x * A); h = aa * h + (dl4.x * xs4.x) * B4.x;
        part = h * C4.x;
        ROR_ADD(part, 0x121); ROR_ADD(part, 0x122); ROR_ADD(part, 0x124); ROR_ADD(part, 0x128);
        if (s == 0) sy[d][j] = part + xs4.x * Dsr;
        aa = __expf(dl4.y * A); h = aa * h + (dl4.y * xs4.y) * B4.y;
        part = h * C4.y;
        ROR_ADD(part, 0x121); ROR_ADD(part, 0x122); ROR_ADD(part, 0x124); ROR_ADD(part, 0x128);
        if (s == 0 && j + 1 < 49) sy[d][j + 1] = part + xs4.y * Dsr;
        aa = __expf(dl4.z * A); h = aa * h + (dl4.z * xs4.z) * B4.z;
        part = h * C4.z;
        ROR_ADD(part, 0x121); ROR_ADD(part, 0x122); ROR_ADD(part, 0x124); ROR_ADD(part, 0x128);
        if (s == 0 && j + 2 < 49) sy[d][j + 2] = part + xs4.z * Dsr;
        aa = __expf(dl4.w * A); h = aa * h + (dl4.w * xs4.w) * B4.w;
        part = h * C4.w;
        ROR_ADD(part, 0x121); ROR_ADD(part, 0x122); ROR_ADD(part, 0x124); ROR_ADD(part, 0x128);
        if (s == 0 && j + 3 < 49) sy[d][j + 3] = part + xs4.w * Dsr;
    }
    __syncthreads();   // all stage reads done -> safe to overwrite head with y
    float* yout = stage + (size_t)blk * WST2;   // y[j][d], 1176 floats, contiguous
    for (int idx = tid; idx < PERK * 49; idx += 384) {
        int j = idx / PERK, d2 = idx - j * PERK;
        yout[idx] = sy[d2][j];
    }
}

// -------- k_yadd: selected windows written DIRECTLY: out = x + p*y (no RMW) --------
__global__ __launch_bounds__(256) void k_yadd(const float* __restrict__ stage,
        const float* __restrict__ x, const int* __restrict__ sel,
        const float* __restrict__ rw, float* __restrict__ out) {
    __shared__ float ytile[CC * 49];
    int qo = blockIdx.x & 255; int b = blockIdx.x >> 8;
    int wsel = sel[b * TOPK + qo];
    float p = rw[b * TOPK + qo];
    // loop 1: gather p*y into ytile (d-fastest enumeration: y reads 96B-contiguous)
    for (int idx = threadIdx.x; idx < CC * 49; idx += 256) {
        int k = idx / 1176; int r1 = idx - k * 1176;
        int u = r1 / 168;   int r2 = r1 - u * 168;
        int wj = r2 / 24;   int d = r2 - wj * 24;
        int rest = qo * 7 + u;
        int b2 = rest & 15; int aw = rest >> 4;
        int wi = aw % 7;    int a = aw / 7;
        int q   = (k & 1) ? (b2 * 16 + a) : (a * 16 + b2);
        int pix = (k & 1) ? (wj * 7 + wi) : (wi * 7 + wj);
        int uu = q * 49 + pix;
        int l = (k >= 2) ? (LL - 1 - uu) : uu;
        int bk = b * 4 + k;
        int t2 = l / 49, jj = l - t2 * 49;
        ytile[(k * PERK + d) * 49 + u * 7 + wj] =
            p * stage[((size_t)(bk * 256 + t2)) * WST2 + jj * PERK + d];
    }
    __syncthreads();
    // loop 2: out = x + ytile, e-ordered (x reads 28B-coalesced, store coalesced)
    float* ob = out + ((size_t)(b * NWIN + wsel) * CC) * 49;
    int gi0 = (wsel >> 5) * 7, gj0 = (wsel & 31) * 7;
    for (int e = threadIdx.x; e < CC * 49; e += 256) {
        int C = e / 49, cell = e - C * 49;
        int u = cell / 7, wj = cell - u * 7;
        float xv = x[(((size_t)b * CC + C) * HH + gi0 + u) * HH + gj0 + wj];
        ob[e] = xv + ytile[e];
    }
}

extern "C" void kernel_launch(void* const* d_in, const int* in_sizes, int n_in,
                              void* d_out, int out_size, void* d_ws, size_t ws_size,
                              hipStream_t stream) {
    const float* x   = (const float*)d_in[0];
    const float* w1  = (const float*)d_in[1];
    const float* b1  = (const float*)d_in[2];
    const float* w2  = (const float*)d_in[3];
    const float* b2  = (const float*)d_in[4];
    const float* xpw = (const float*)d_in[5];
    const float* dtw = (const float*)d_in[6];
    const float* dtb = (const float*)d_in[7];
    const float* alg = (const float*)d_in[8];
    const float* dsv = (const float*)d_in[9];
    float* out = (float*)d_out;
    float* ws  = (float*)d_ws;

    float* pooled = ws + OFF_POOL;
    float* probs  = ws + OFF_PROB;
    float* rwv    = ws + OFF_RW;
    int*   rank   = (int*)(ws + OFF_RANK);
    int*   sel    = (int*)(ws + OFF_SEL);
    float* wcomb  = ws + OFF_WEFF;
    float* cP  = ws + OFF_CP;       // also hin after k_carry
    float* cS  = ws + OFF_CS;
    float* xsd = ws + OFF_XSD;
    float* stage = ws + OFF_STG;

    k_pool  <<<BBATCH * CC, 256, 0, stream>>>(x, pooled);
    k_route <<<BBATCH, 1024, 0, stream>>>(pooled, w1, b1, w2, b2, xpw, dtw, wcomb, probs);
    k_rank2 <<<BBATCH * 16, 64, 0, stream>>>(probs, rwv, rank, sel);
    k_gather<<<2048, 256, 0, stream>>>(x, sel, xsd);
    k_prodD <<<NBK * TCH, 384, 0, stream>>>(xsd, wcomb, dtb, alg, stage, cP, cS);
    k_carry <<<48, 256, 0, stream>>>(cP, cS, cP);     // hin aliases cP (read-before-write)
    k_base  <<<BBATCH * CC * NHW, 64, 0, stream>>>(x, probs, rank, out);
    k_scan2 <<<NBK * TCH, 384, 0, stream>>>(alg, dsv, cP, xsd, stage);
    k_yadd  <<<BBATCH * TOPK, 256, 0, stream>>>(stage, x, sel, rwv, out);
}

// Round 11
// 487.791 us; speedup vs baseline: 1.1973x; 1.0352x over previous
//
#include <hip/hip_runtime.h>
#include <math.h>

// Problem constants
#define BBATCH 8
#define CC 96
#define HH 224
#define NHW 32            // 224/7 windows per side
#define NWIN 1024
#define TOPK 256
#define PERK 24
#define DST 16
#define DTR 6
#define LL 12544          // 256*49
#define LCP 52            // padded row length (49 used + 3 zero pad)
#define NG 13             // float4 groups per row
#define TCH 256           // one chunk = ONE scan window (49 steps)
#define NBK 32            // B*4 directions
#define XROW 1248         // xs floats per window: 24 x 52
#define WST2 2912         // stage floats per window: 56 rows x 52 (delta,B,C)

// workspace offsets (floats) — total 41,190,656 floats = 164.8 MB (proven available)
#define OFF_POOL 0
#define OFF_LOG  786432
#define OFF_PROB 794624
#define OFF_RW   802816
#define OFF_RANK 804864
#define OFF_SEL  813056
#define OFF_WEFF 815104
#define OFF_CP   820480      // 3,145,728; reused as hin (read-before-write in k_carry)
#define OFF_CS   3966208     // 3,145,728
#define OFF_XSD  7111936     // 10,223,616: xs dense [8192][24][52]
#define OFF_STG  17335552    // 23,855,104: stage [8192][56][52]; y aliased into head

// DPP row_ror:N add — 16-lane full-sum reduction on the VALU pipe (not DS)
#define ROR_ADD(v, CTRL) \
    v += __int_as_float(__builtin_amdgcn_update_dpp(0, __float_as_int(v), CTRL, 0xf, 0xf, true))

// -------- k_weff: fold dt_proj into x_proj: Wcomb[k][56][24] --------
__global__ void k_weff(const float* __restrict__ xpw, const float* __restrict__ dtw,
                       float* __restrict__ wcomb) {
    int i = blockIdx.x * blockDim.x + threadIdx.x;
    if (i >= 4 * 56 * PERK) return;
    int k = i / (56 * PERK), rem = i - k * (56 * PERK);
    int row = rem / PERK, c = rem - row * PERK;
    float v;
    if (row < PERK) {
        v = 0.f;
        #pragma unroll
        for (int r = 0; r < DTR; ++r)
            v += dtw[(k * PERK + row) * DTR + r] * xpw[(k * 38 + r) * PERK + c];
    } else {
        v = xpw[(k * 38 + (row - PERK + DTR)) * PERK + c];
    }
    wcomb[i] = v;
}

// -------- K1: window pooling: pooledT[b][c][w] --------
__global__ void k_pool(const float* __restrict__ x, float* __restrict__ pooled) {
    int bc = blockIdx.x;                 // b*96+c
    const float* xp = x + (size_t)bc * HH * HH;
    float* pp = pooled + (size_t)bc * NWIN;
    for (int w = threadIdx.x; w < NWIN; w += blockDim.x) {
        int wr = w >> 5, wc = w & 31;
        const float* base = xp + (wr * 7) * HH + wc * 7;
        float s = 0.f;
        #pragma unroll
        for (int i = 0; i < 7; ++i) {
            #pragma unroll
            for (int j = 0; j < 7; ++j) s += base[i * HH + j];
        }
        pp[w] = s * (1.0f / 49.0f);
    }
}

// -------- k_router: MLP logits, 128 blocks x 64 threads (one window per thread) --------
__global__ __launch_bounds__(64) void k_router(
        const float* __restrict__ pooled,
        const float* __restrict__ w1, const float* __restrict__ b1,
        const float* __restrict__ w2, const float* __restrict__ b2,
        float* __restrict__ logits) {
    __shared__ float sw1[PERK * CC];
    __shared__ float sb1[PERK];
    __shared__ float sw2[PERK];
    int b = blockIdx.x >> 4, slice = blockIdx.x & 15;
    int tid = threadIdx.x;
    for (int i = tid; i < PERK * CC; i += 64) sw1[i] = w1[i];
    if (tid < PERK) { sb1[tid] = b1[tid]; sw2[tid] = w2[tid]; }
    __syncthreads();
    int w = slice * 64 + tid;
    float hid[PERK];
    #pragma unroll
    for (int j = 0; j < PERK; ++j) hid[j] = sb1[j];
    const float* pp = pooled + (size_t)b * CC * NWIN + w;
    for (int c = 0; c < CC; ++c) {
        float pv = pp[(size_t)c * NWIN];
        #pragma unroll
        for (int j = 0; j < PERK; ++j) hid[j] += pv * sw1[j * CC + c];
    }
    float lg = b2[0];
    #pragma unroll
    for (int j = 0; j < PERK; ++j) {
        float hv = hid[j];
        float g = 0.5f * hv * (1.0f + erff(hv * 0.7071067811865476f));
        lg += g * sw2[j];
    }
    logits[b * NWIN + w] = lg;
}

// -------- k_rankF: fused softmax + stable descending rank (128 blocks x 64) --------
__global__ __launch_bounds__(64) void k_rankF(const float* __restrict__ logits,
        float* __restrict__ probs, float* __restrict__ rw,
        int* __restrict__ rank, int* __restrict__ sel) {
    __shared__ __attribute__((aligned(16))) float sp[NWIN];
    __shared__ float red[64];
    int b = blockIdx.x >> 4, slice = blockIdx.x & 15;
    int tid = threadIdx.x;
    // load logits row
    for (int i = tid; i < NWIN / 4; i += 64)
        ((float4*)sp)[i] = ((const float4*)(logits + (size_t)b * NWIN))[i];
    __syncthreads();
    // max reduce (16 elems/thread, then 64-wide tree)
    float m = -1e30f;
    for (int i = tid; i < NWIN; i += 64) m = fmaxf(m, sp[i]);
    red[tid] = m; __syncthreads();
    for (int o = 32; o > 0; o >>= 1) { if (tid < o) red[tid] = fmaxf(red[tid], red[tid + o]); __syncthreads(); }
    float mx = red[0]; __syncthreads();
    // exp in place
    for (int i = tid; i < NWIN; i += 64) sp[i] = expf(sp[i] - mx);
    __syncthreads();
    // sum reduce
    float s = 0.f;
    for (int i = tid; i < NWIN; i += 64) s += sp[i];
    red[tid] = s; __syncthreads();
    for (int o = 32; o > 0; o >>= 1) { if (tid < o) red[tid] += red[tid + o]; __syncthreads(); }
    float sum = red[0]; __syncthreads();
    // scale to probs in place (identical values in all 16 blocks of this b)
    for (int i = tid; i < NWIN; i += 64) sp[i] = sp[i] / sum;
    __syncthreads();
    int w = slice * 64 + tid;
    float p = sp[w];
    probs[b * NWIN + w] = p;
    int r = 0;
    for (int j = 0; j < NWIN; j += 4) {
        float4 pj = *(const float4*)&sp[j];
        r += (int)((pj.x > p) || (pj.x == p && (j + 0) < w));
        r += (int)((pj.y > p) || (pj.y == p && (j + 1) < w));
        r += (int)((pj.z > p) || (pj.z == p && (j + 2) < w));
        r += (int)((pj.w > p) || (pj.w == p && (j + 3) < w));
    }
    rank[b * NWIN + w] = r;
    if (r < TOPK) { sel[b * TOPK + r] = w; rw[b * TOPK + r] = p; }
}

// softplus via hardware exp/log
__device__ __forceinline__ float softplus_f(float v) {
    return fmaxf(v, 0.f) + __logf(1.0f + __expf(-fabsf(v)));
}

// chunk t (= scan-window index) -> selected-window id
__device__ __forceinline__ int window_wsel(const int* sel, int b, int k, int t) {
    int qscan = (k >= 2) ? (255 - t) : t;
    int selidx = (k & 1) ? (((qscan & 15) << 4) | (qscan >> 4)) : qscan;
    return sel[b * TOPK + selidx];
}

// -------- k_gather: scattered x -> dense xs [blk][24][52], barrier-free streaming --------
__global__ __launch_bounds__(256) void k_gather(const float* __restrict__ x,
        const int* __restrict__ sel, float* __restrict__ xsd) {
    const int total = NBK * TCH * XROW;   // 10,223,616
    for (int e = blockIdx.x * 256 + threadIdx.x; e < total; e += gridDim.x * 256) {
        int blk = e / XROW;
        int rem = e - blk * XROW;
        int d2 = rem / LCP, j = rem - d2 * LCP;
        float v = 0.f;
        if (j < 49) {
            int t = blk & 255, bk = blk >> 8, k = bk & 3, b = bk >> 2;
            int wsel = window_wsel(sel, b, k, t);
            int pix = (k >= 2) ? 48 - j : j;
            int q7 = pix / 7, r7 = pix - q7 * 7;
            int wi = (k & 1) ? r7 : q7;
            int wj = (k & 1) ? q7 : r7;
            v = x[(((size_t)b * CC + 4 * d2 + k) * HH + (wsel >> 5) * 7 + wi) * HH
                  + (wsel & 31) * 7 + wj];
        }
        xsd[e] = v;
    }
}

// -------- k_prodD: dense xs -> proj (delta,B,C) staged + phase-1 carries --------
__global__ __launch_bounds__(384, 4) void k_prodD(
        const float* __restrict__ xsd, const float* __restrict__ wcomb,
        const float* __restrict__ dtb, const float* __restrict__ alogs,
        float* __restrict__ stage, float* __restrict__ carrP, float* __restrict__ carrS) {
    __shared__ __attribute__((aligned(16))) float sxs[PERK][LCP];
    __shared__ __attribute__((aligned(16))) float sprj[56][LCP];  // 0..23 delta, 24..39 B, 40..55 C
    __shared__ float swt[56 * PERK];
    __shared__ float sbias[PERK];
    int blk = blockIdx.x;
    int bk = blk >> 8; int k = bk & 3;
    int tid = threadIdx.x;
    const float4* xin = (const float4*)(xsd + (size_t)blk * XROW);
    for (int i = tid; i < XROW / 4; i += 384) ((float4*)sxs)[i] = xin[i];
    for (int i = tid; i < 56 * PERK; i += 384) swt[i] = wcomb[k * (56 * PERK) + i];
    if (tid < PERK) sbias[tid] = dtb[k * PERK + tid];
    if (tid < 168) {                    // zero pad columns 49..51 of sprj
        int r = tid / 3, j = 49 + tid % 3;
        sprj[r][j] = 0.f;
    }
    int d = tid >> 4, s = tid & 15;
    float A = -__expf(alogs[(k * PERK + d) * DST + s]);
    __syncthreads();
    for (int idx = tid; idx < 56 * NG; idx += 384) {
        int row = idx / NG, g = idx - row * NG; int j = g * 4;
        float bs = (row < PERK) ? sbias[row] : 0.f;
        float ax = bs, ay = bs, az = bs, aw = bs;
        #pragma unroll
        for (int d2 = 0; d2 < PERK; ++d2) {
            float w = swt[row * PERK + d2];
            float4 v = *(const float4*)&sxs[d2][j];
            ax += w * v.x; ay += w * v.y; az += w * v.z; aw += w * v.w;
        }
        if (row < PERK) {
            ax = softplus_f(ax); ay = softplus_f(ay); az = softplus_f(az); aw = softplus_f(aw);
        }
        float* dst = &sprj[row][j];
        if (g < 12) { float4 o = {ax, ay, az, aw}; *(float4*)dst = o; }
        else dst[0] = ax;
    }
    __syncthreads();
    float4* sg = (float4*)(stage + (size_t)blk * WST2);
    const float4* sp4 = (const float4*)&sprj[0][0];
    for (int i = tid; i < WST2 / 4; i += 384) sg[i] = sp4[i];
    float P = 1.f, S = 0.f;
    for (int g = 0; g < NG; ++g) {
        int j = g * 4;
        float4 dl4 = *(const float4*)&sprj[d][j];        // pads = 0
        float4 xs4 = *(const float4*)&sxs[d][j];
        float4 B4  = *(const float4*)&sprj[24 + s][j];
        float aa;
        aa = __expf(dl4.x * A); S = aa * S + (dl4.x * xs4.x) * B4.x; P *= aa;
        aa = __expf(dl4.y * A); S = aa * S + (dl4.y * xs4.y) * B4.y; P *= aa;
        aa = __expf(dl4.z * A); S = aa * S + (dl4.z * xs4.z) * B4.z; P *= aa;
        aa = __expf(dl4.w * A); S = aa * S + (dl4.w * xs4.w) * B4.w; P *= aa;
    }
    size_t cidx = (size_t)blk * 384 + tid;
    carrP[cidx] = P; carrS[cidx] = S;
}

// -------- k_carry: scan across 256 windows (hin may alias carrP: read-before-write) --------
__global__ void k_carry(const float* carrP, const float* carrS, float* hin) {
    int gid = blockIdx.x * blockDim.x + threadIdx.x;   // 12288
    int bk = gid / 384, ds = gid - bk * 384;
    float Hv = 0.f;
    for (int t = 0; t < TCH; ++t) {
        size_t idx = ((size_t)bk * TCH + t) * 384 + ds;
        float pv = carrP[idx], sv = carrS[idx];
        hin[idx] = Hv;
        Hv = pv * Hv + sv;
    }
}

// -------- k_base: out = x*(1+p) for UNSELECTED windows only (selected written by k_yadd) --------
__global__ __launch_bounds__(64) void k_base(const float* __restrict__ x,
        const float* __restrict__ probs, const int* __restrict__ rank,
        float* __restrict__ out) {
    int wr = blockIdx.x % NHW; int bc = blockIdx.x / NHW;
    int b = bc / CC;
    __shared__ float buf[7 * HH];
    __shared__ float fmul[NHW];
    __shared__ int   fsel[NHW];
    int tid = threadIdx.x;
    const float* xp = x + ((size_t)bc * HH + wr * 7) * HH;
    for (int i = tid; i < 7 * HH; i += 64) buf[i] = xp[i];
    if (tid < NHW) {
        int w = wr * NHW + tid;
        fsel[tid] = (rank[b * NWIN + w] < TOPK);
        fmul[tid] = 1.0f + probs[b * NWIN + w];
    }
    __syncthreads();
    int c = bc - b * CC;
    for (int idx = tid; idx < NHW * 49; idx += 64) {
        int wc = idx / 49, r = idx - wc * 49;
        if (fsel[wc]) continue;
        int ri = r / 7, rj = r - ri * 7;
        float v = buf[ri * HH + wc * 7 + rj];
        int w = wr * NHW + wc;
        out[(((size_t)b * NWIN + w) * CC + c) * 49 + r] = v * fmul[wc];
    }
}

// -------- k_scan2: recurrence only; depth-2 prefetch pipeline; y into stage head --------
__global__ __launch_bounds__(384, 4) void k_scan2(
        const float* __restrict__ alogs, const float* __restrict__ dsv,
        const float* __restrict__ hin, const float* __restrict__ xsd,
        float* __restrict__ stage) {
    __shared__ __attribute__((aligned(16))) float sy[PERK][LCP];
    int blk = blockIdx.x;
    int bk = blk >> 8; int k = bk & 3;
    int tid = threadIdx.x;
    int d = tid >> 4, s = tid & 15;
    float A = -__expf(alogs[(k * PERK + d) * DST + s]);
    float Dsr = dsv[k * PERK + d];
    size_t cidx = (size_t)blk * 384 + tid;
    float h = hin[cidx];
    const float* sg = stage + (size_t)blk * WST2;
    const float* pdl = sg + d * LCP;
    const float* pB  = sg + (24 + s) * LCP;
    const float* pC  = sg + (40 + s) * LCP;
    const float* pxs = xsd + (size_t)blk * XROW + d * LCP;
    // depth-2 software pipeline: groups g (current), g+1 (staged), g+2 (prefetching)
    float4 dlC = *(const float4*)(pdl);     float4 xsC = *(const float4*)(pxs);
    float4 BC_ = *(const float4*)(pB);      float4 CC_ = *(const float4*)(pC);
    float4 dlN = *(const float4*)(pdl + 4); float4 xsN = *(const float4*)(pxs + 4);
    float4 BN_ = *(const float4*)(pB + 4);  float4 CN_ = *(const float4*)(pC + 4);
    for (int g = 0; g < NG; ++g) {
        float4 dl4 = dlC, xs4 = xsC, B4 = BC_, C4 = CC_;
        dlC = dlN; xsC = xsN; BC_ = BN_; CC_ = CN_;
        if (g + 2 < NG) {
            int jn = (g + 2) * 4;
            dlN = *(const float4*)(pdl + jn); xsN = *(const float4*)(pxs + jn);
            BN_ = *(const float4*)(pB + jn);  CN_ = *(const float4*)(pC + jn);
        }
        int j = g * 4;
        float aa, part;
        aa = __expf(dl4.x * A); h = aa * h + (dl4.x * xs4.x) * B4.x;
        part = h * C4.x;
        ROR_ADD(part, 0x121); ROR_ADD(part, 0x122); ROR_ADD(part, 0x124); ROR_ADD(part, 0x128);
        if (s == 0) sy[d][j] = part + xs4.x * Dsr;
        aa = __expf(dl4.y * A); h = aa * h + (dl4.y * xs4.y) * B4.y;
        part = h * C4.y;
        ROR_ADD(part, 0x121); ROR_ADD(part, 0x122); ROR_ADD(part, 0x124); ROR_ADD(part, 0x128);
        if (s == 0 && j + 1 < 49) sy[d][j + 1] = part + xs4.y * Dsr;
        aa = __expf(dl4.z * A); h = aa * h + (dl4.z * xs4.z) * B4.z;
        part = h * C4.z;
        ROR_ADD(part, 0x121); ROR_ADD(part, 0x122); ROR_ADD(part, 0x124); ROR_ADD(part, 0x128);
        if (s == 0 && j + 2 < 49) sy[d][j + 2] = part + xs4.z * Dsr;
        aa = __expf(dl4.w * A); h = aa * h + (dl4.w * xs4.w) * B4.w;
        part = h * C4.w;
        ROR_ADD(part, 0x121); ROR_ADD(part, 0x122); ROR_ADD(part, 0x124); ROR_ADD(part, 0x128);
        if (s == 0 && j + 3 < 49) sy[d][j + 3] = part + xs4.w * Dsr;
    }
    __syncthreads();   // all stage reads done -> safe to overwrite head with y
    float* yout = stage + (size_t)blk * WST2;   // y[j][d], 1176 floats, contiguous
    for (int idx = tid; idx < PERK * 49; idx += 384) {
        int j = idx / PERK, d2 = idx - j * PERK;
        yout[idx] = sy[d2][j];
    }
}

// -------- k_yadd: selected windows written DIRECTLY: out = x + p*y (no RMW) --------
__global__ __launch_bounds__(256) void k_yadd(const float* __restrict__ stage,
        const float* __restrict__ x, const int* __restrict__ sel,
        const float* __restrict__ rw, float* __restrict__ out) {
    __shared__ float ytile[CC * 49];
    int qo = blockIdx.x & 255; int b = blockIdx.x >> 8;
    int wsel = sel[b * TOPK + qo];
    float p = rw[b * TOPK + qo];
    // loop 1: gather p*y into ytile (d-fastest enumeration: y reads 96B-contiguous)
    for (int idx = threadIdx.x; idx < CC * 49; idx += 256) {
        int k = idx / 1176; int r1 = idx - k * 1176;
        int u = r1 / 168;   int r2 = r1 - u * 168;
        int wj = r2 / 24;   int d = r2 - wj * 24;
        int rest = qo * 7 + u;
        int b2 = rest & 15; int aw = rest >> 4;
        int wi = aw % 7;    int a = aw / 7;
        int q   = (k & 1) ? (b2 * 16 + a) : (a * 16 + b2);
        int pix = (k & 1) ? (wj * 7 + wi) : (wi * 7 + wj);
        int uu = q * 49 + pix;
        int l = (k >= 2) ? (LL - 1 - uu) : uu;
        int bk = b * 4 + k;
        int t2 = l / 49, jj = l - t2 * 49;
        ytile[(k * PERK + d) * 49 + u * 7 + wj] =
            p * stage[((size_t)(bk * 256 + t2)) * WST2 + jj * PERK + d];
    }
    __syncthreads();
    // loop 2: out = x + ytile, e-ordered (x reads 28B-coalesced, store coalesced)
    float* ob = out + ((size_t)(b * NWIN + wsel) * CC) * 49;
    int gi0 = (wsel >> 5) * 7, gj0 = (wsel & 31) * 7;
    for (int e = threadIdx.x; e < CC * 49; e += 256) {
        int C = e / 49, cell = e - C * 49;
        int u = cell / 7, wj = cell - u * 7;
        float xv = x[(((size_t)b * CC + C) * HH + gi0 + u) * HH + gj0 + wj];
        ob[e] = xv + ytile[e];
    }
}

extern "C" void kernel_launch(void* const* d_in, const int* in_sizes, int n_in,
                              void* d_out, int out_size, void* d_ws, size_t ws_size,
                              hipStream_t stream) {
    const float* x   = (const float*)d_in[0];
    const float* w1  = (const float*)d_in[1];
    const float* b1  = (const float*)d_in[2];
    const float* w2  = (const float*)d_in[3];
    const float* b2  = (const float*)d_in[4];
    const float* xpw = (const float*)d_in[5];
    const float* dtw = (const float*)d_in[6];
    const float* dtb = (const float*)d_in[7];
    const float* alg = (const float*)d_in[8];
    const float* dsv = (const float*)d_in[9];
    float* out = (float*)d_out;
    float* ws  = (float*)d_ws;

    float* pooled = ws + OFF_POOL;
    float* logits = ws + OFF_LOG;
    float* probs  = ws + OFF_PROB;
    float* rwv    = ws + OFF_RW;
    int*   rank   = (int*)(ws + OFF_RANK);
    int*   sel    = (int*)(ws + OFF_SEL);
    float* wcomb  = ws + OFF_WEFF;
    float* cP  = ws + OFF_CP;       // also hin after k_carry
    float* cS  = ws + OFF_CS;
    float* xsd = ws + OFF_XSD;
    float* stage = ws + OFF_STG;

    k_pool  <<<BBATCH * CC, 256, 0, stream>>>(x, pooled);
    k_router<<<BBATCH * 16, 64, 0, stream>>>(pooled, w1, b1, w2, b2, logits);
    k_rankF <<<BBATCH * 16, 64, 0, stream>>>(logits, probs, rwv, rank, sel);
    k_weff  <<<(4 * 56 * PERK + 255) / 256, 256, 0, stream>>>(xpw, dtw, wcomb);
    k_gather<<<2048, 256, 0, stream>>>(x, sel, xsd);
    k_prodD <<<NBK * TCH, 384, 0, stream>>>(xsd, wcomb, dtb, alg, stage, cP, cS);
    k_carry <<<48, 256, 0, stream>>>(cP, cS, cP);     // hin aliases cP (read-before-write)
    k_base  <<<BBATCH * CC * NHW, 64, 0, stream>>>(x, probs, rank, out);
    k_scan2 <<<NBK * TCH, 384, 0, stream>>>(alg, dsv, cP, xsd, stage);
    k_yadd  <<<BBATCH * TOPK, 256, 0, stream>>>(stage, x, sel, rwv, out);
}

// Round 12
// 484.268 us; speedup vs baseline: 1.2060x; 1.0073x over previous
//
#include <hip/hip_runtime.h>
#include <math.h>

// Problem constants
#define BBATCH 8
#define CC 96
#define HH 224
#define NHW 32            // 224/7 windows per side
#define NWIN 1024
#define TOPK 256
#define PERK 24
#define DST 16
#define DTR 6
#define LL 12544          // 256*49
#define LCP 52            // padded row length (49 used + 3 zero pad)
#define NG 13             // float4 groups per row
#define TCH 256           // one chunk = ONE scan window (49 steps)
#define NBK 32            // B*4 directions
#define XROW 1248         // xs floats per window: 24 x 52 (y reuses head: 1176)
#define WST2 2912         // fallback stage floats per window: 56 rows x 52
#define WST3 4000         // transposed stage: P[25][24][4] (2400) + Q[25][16][4] (1600)

// workspace offsets (floats)
#define OFF_POOL 0
#define OFF_LOG  786432
#define OFF_PROB 794624
#define OFF_RW   802816
#define OFF_RANK 804864
#define OFF_SEL  813056
#define OFF_WEFF 815104
#define OFF_CP   820480      // 3,145,728; reused as hin (read-before-write in k_carry)
#define OFF_CS   3966208     // 3,145,728
#define OFF_XSD  7111936     // 10,223,616: xs dense [8192][24][52]; y written into head later
#define OFF_STG  17335552    // big: 8192*4000 = 32,768,000 | fallback: 8192*2912
#define NEED_T   ((size_t)(17335552 + 8192 * WST3) * 4)   // 200.4 MB
#define NEED_F   ((size_t)(17335552 + 8192 * WST2) * 4)   // 164.8 MB (proven available)

// DPP row_ror:N add — 16-lane full-sum reduction on the VALU pipe (not DS)
#define ROR_ADD(v, CTRL) \
    v += __int_as_float(__builtin_amdgcn_update_dpp(0, __float_as_int(v), CTRL, 0xf, 0xf, true))

// -------- k_weff: fold dt_proj into x_proj: Wcomb[k][56][24] --------
__global__ void k_weff(const float* __restrict__ xpw, const float* __restrict__ dtw,
                       float* __restrict__ wcomb) {
    int i = blockIdx.x * blockDim.x + threadIdx.x;
    if (i >= 4 * 56 * PERK) return;
    int k = i / (56 * PERK), rem = i - k * (56 * PERK);
    int row = rem / PERK, c = rem - row * PERK;
    float v;
    if (row < PERK) {
        v = 0.f;
        #pragma unroll
        for (int r = 0; r < DTR; ++r)
            v += dtw[(k * PERK + row) * DTR + r] * xpw[(k * 38 + r) * PERK + c];
    } else {
        v = xpw[(k * 38 + (row - PERK + DTR)) * PERK + c];
    }
    wcomb[i] = v;
}

// -------- K1: window pooling: pooledT[b][c][w] --------
__global__ void k_pool(const float* __restrict__ x, float* __restrict__ pooled) {
    int bc = blockIdx.x;                 // b*96+c
    const float* xp = x + (size_t)bc * HH * HH;
    float* pp = pooled + (size_t)bc * NWIN;
    for (int w = threadIdx.x; w < NWIN; w += blockDim.x) {
        int wr = w >> 5, wc = w & 31;
        const float* base = xp + (wr * 7) * HH + wc * 7;
        float s = 0.f;
        #pragma unroll
        for (int i = 0; i < 7; ++i) {
            #pragma unroll
            for (int j = 0; j < 7; ++j) s += base[i * HH + j];
        }
        pp[w] = s * (1.0f / 49.0f);
    }
}

// -------- k_router: MLP logits, 128 blocks x 64 threads --------
__global__ __launch_bounds__(64) void k_router(
        const float* __restrict__ pooled,
        const float* __restrict__ w1, const float* __restrict__ b1,
        const float* __restrict__ w2, const float* __restrict__ b2,
        float* __restrict__ logits) {
    __shared__ float sw1[PERK * CC];
    __shared__ float sb1[PERK];
    __shared__ float sw2[PERK];
    int b = blockIdx.x >> 4, slice = blockIdx.x & 15;
    int tid = threadIdx.x;
    for (int i = tid; i < PERK * CC; i += 64) sw1[i] = w1[i];
    if (tid < PERK) { sb1[tid] = b1[tid]; sw2[tid] = w2[tid]; }
    __syncthreads();
    int w = slice * 64 + tid;
    float hid[PERK];
    #pragma unroll
    for (int j = 0; j < PERK; ++j) hid[j] = sb1[j];
    const float* pp = pooled + (size_t)b * CC * NWIN + w;
    for (int c = 0; c < CC; ++c) {
        float pv = pp[(size_t)c * NWIN];
        #pragma unroll
        for (int j = 0; j < PERK; ++j) hid[j] += pv * sw1[j * CC + c];
    }
    float lg = b2[0];
    #pragma unroll
    for (int j = 0; j < PERK; ++j) {
        float hv = hid[j];
        float g = 0.5f * hv * (1.0f + erff(hv * 0.7071067811865476f));
        lg += g * sw2[j];
    }
    logits[b * NWIN + w] = lg;
}

// -------- k_rankF: fused softmax + stable descending rank (128 blocks x 64) --------
__global__ __launch_bounds__(64) void k_rankF(const float* __restrict__ logits,
        float* __restrict__ probs, float* __restrict__ rw,
        int* __restrict__ rank, int* __restrict__ sel) {
    __shared__ __attribute__((aligned(16))) float sp[NWIN];
    __shared__ float red[64];
    int b = blockIdx.x >> 4, slice = blockIdx.x & 15;
    int tid = threadIdx.x;
    for (int i = tid; i < NWIN / 4; i += 64)
        ((float4*)sp)[i] = ((const float4*)(logits + (size_t)b * NWIN))[i];
    __syncthreads();
    float m = -1e30f;
    for (int i = tid; i < NWIN; i += 64) m = fmaxf(m, sp[i]);
    red[tid] = m; __syncthreads();
    for (int o = 32; o > 0; o >>= 1) { if (tid < o) red[tid] = fmaxf(red[tid], red[tid + o]); __syncthreads(); }
    float mx = red[0]; __syncthreads();
    for (int i = tid; i < NWIN; i += 64) sp[i] = expf(sp[i] - mx);
    __syncthreads();
    float s = 0.f;
    for (int i = tid; i < NWIN; i += 64) s += sp[i];
    red[tid] = s; __syncthreads();
    for (int o = 32; o > 0; o >>= 1) { if (tid < o) red[tid] += red[tid + o]; __syncthreads(); }
    float sum = red[0]; __syncthreads();
    for (int i = tid; i < NWIN; i += 64) sp[i] = sp[i] / sum;
    __syncthreads();
    int w = slice * 64 + tid;
    float p = sp[w];
    probs[b * NWIN + w] = p;
    int r = 0;
    for (int j = 0; j < NWIN; j += 4) {
        float4 pj = *(const float4*)&sp[j];
        r += (int)((pj.x > p) || (pj.x == p && (j + 0) < w));
        r += (int)((pj.y > p) || (pj.y == p && (j + 1) < w));
        r += (int)((pj.z > p) || (pj.z == p && (j + 2) < w));
        r += (int)((pj.w > p) || (pj.w == p && (j + 3) < w));
    }
    rank[b * NWIN + w] = r;
    if (r < TOPK) { sel[b * TOPK + r] = w; rw[b * TOPK + r] = p; }
}

// softplus via hardware exp/log
__device__ __forceinline__ float softplus_f(float v) {
    return fmaxf(v, 0.f) + __logf(1.0f + __expf(-fabsf(v)));
}

// chunk t (= scan-window index) -> selected-window id
__device__ __forceinline__ int window_wsel(const int* sel, int b, int k, int t) {
    int qscan = (k >= 2) ? (255 - t) : t;
    int selidx = (k & 1) ? (((qscan & 15) << 4) | (qscan >> 4)) : qscan;
    return sel[b * TOPK + selidx];
}

// -------- k_gather: scattered x -> dense xs [blk][24][52], barrier-free streaming --------
__global__ __launch_bounds__(256) void k_gather(const float* __restrict__ x,
        const int* __restrict__ sel, float* __restrict__ xsd) {
    const int total = NBK * TCH * XROW;   // 10,223,616
    for (int e = blockIdx.x * 256 + threadIdx.x; e < total; e += gridDim.x * 256) {
        int blk = e / XROW;
        int rem = e - blk * XROW;
        int d2 = rem / LCP, j = rem - d2 * LCP;
        float v = 0.f;
        if (j < 49) {
            int t = blk & 255, bk = blk >> 8, k = bk & 3, b = bk >> 2;
            int wsel = window_wsel(sel, b, k, t);
            int pix = (k >= 2) ? 48 - j : j;
            int q7 = pix / 7, r7 = pix - q7 * 7;
            int wi = (k & 1) ? r7 : q7;
            int wj = (k & 1) ? q7 : r7;
            v = x[(((size_t)b * CC + 4 * d2 + k) * HH + (wsel >> 5) * 7 + wi) * HH
                  + (wsel & 31) * 7 + wj];
        }
        xsd[e] = v;
    }
}

// shared projection body: fills sxs + sprj (0..23 delta, 24..39 B, 40..55 C)
__device__ __forceinline__ void proj_body(
        float (*sxs)[LCP], float (*sprj)[LCP], float* swt, float* sbias,
        const float* xsd, const float* wcomb, const float* dtb,
        int blk, int k, int tid) {
    const float4* xin = (const float4*)(xsd + (size_t)blk * XROW);
    for (int i = tid; i < XROW / 4; i += 384) ((float4*)sxs)[i] = xin[i];
    for (int i = tid; i < 56 * PERK; i += 384) swt[i] = wcomb[k * (56 * PERK) + i];
    if (tid < PERK) sbias[tid] = dtb[k * PERK + tid];
    if (tid < 168) { int r = tid / 3, j = 49 + tid % 3; sprj[r][j] = 0.f; }
    __syncthreads();
    for (int idx = tid; idx < 56 * NG; idx += 384) {
        int row = idx / NG, g = idx - row * NG; int j = g * 4;
        float bs = (row < PERK) ? sbias[row] : 0.f;
        float ax = bs, ay = bs, az = bs, aw = bs;
        #pragma unroll
        for (int d2 = 0; d2 < PERK; ++d2) {
            float w = swt[row * PERK + d2];
            float4 v = *(const float4*)&sxs[d2][j];
            ax += w * v.x; ay += w * v.y; az += w * v.z; aw += w * v.w;
        }
        if (row < PERK) {
            ax = softplus_f(ax); ay = softplus_f(ay); az = softplus_f(az); aw = softplus_f(aw);
        }
        float* dst = &sprj[row][j];
        if (g < 12) { float4 o = {ax, ay, az, aw}; *(float4*)dst = o; }
        else dst[0] = ax;
    }
    __syncthreads();
}

// shared phase-1 carry computation
__device__ __forceinline__ void carry_body(
        float (*sxs)[LCP], float (*sprj)[LCP], const float* alogs,
        int blk, int k, int tid, float* carrP, float* carrS) {
    int d = tid >> 4, s = tid & 15;
    float A = -__expf(alogs[(k * PERK + d) * DST + s]);
    float P = 1.f, S = 0.f;
    for (int g = 0; g < NG; ++g) {
        int j = g * 4;
        float4 dl4 = *(const float4*)&sprj[d][j];        // pads = 0
        float4 xs4 = *(const float4*)&sxs[d][j];
        float4 B4  = *(const float4*)&sprj[24 + s][j];
        float aa;
        aa = __expf(dl4.x * A); S = aa * S + (dl4.x * xs4.x) * B4.x; P *= aa;
        aa = __expf(dl4.y * A); S = aa * S + (dl4.y * xs4.y) * B4.y; P *= aa;
        aa = __expf(dl4.z * A); S = aa * S + (dl4.z * xs4.z) * B4.z; P *= aa;
        aa = __expf(dl4.w * A); S = aa * S + (dl4.w * xs4.w) * B4.w; P *= aa;
    }
    size_t cidx = (size_t)blk * 384 + tid;
    carrP[cidx] = P; carrS[cidx] = S;
}

// -------- k_prodT: proj -> TRANSPOSED stage (P[25][24][4], Q[25][16][4]) + carries --------
__global__ __launch_bounds__(384, 4) void k_prodT(
        const float* __restrict__ xsd, const float* __restrict__ wcomb,
        const float* __restrict__ dtb, const float* __restrict__ alogs,
        float* __restrict__ stage, float* __restrict__ carrP, float* __restrict__ carrS) {
    __shared__ __attribute__((aligned(16))) float sxs[PERK][LCP];
    __shared__ __attribute__((aligned(16))) float sprj[56][LCP];
    __shared__ float swt[56 * PERK];
    __shared__ float sbias[PERK];
    int blk = blockIdx.x; int k = (blk >> 8) & 3;
    int tid = threadIdx.x;
    proj_body(sxs, sprj, swt, sbias, xsd, wcomb, dtb, blk, k, tid);
    // transposed dump: j-pair-major, wave-coalesced consumers
    float4* sgP = (float4*)(stage + (size_t)blk * WST3);
    float4* sgQ = sgP + 600;
    for (int tsk = tid; tsk < 600; tsk += 384) {       // P: (dl,xs) pairs
        int jp = tsk / 24, d2 = tsk - jp * 24;
        int j0 = 2 * jp, j1 = j0 + 1;                  // j1=49 -> sprj/sxs pads = 0
        float4 o = { sprj[d2][j0], sxs[d2][j0], sprj[d2][j1], sxs[d2][j1] };
        sgP[tsk] = o;
    }
    for (int tsk = tid; tsk < 400; tsk += 384) {       // Q: (B,C) pairs
        int jp = tsk / 16, s2 = tsk - jp * 16;
        int j0 = 2 * jp, j1 = j0 + 1;
        float4 o = { sprj[24 + s2][j0], sprj[40 + s2][j0], sprj[24 + s2][j1], sprj[40 + s2][j1] };
        sgQ[tsk] = o;
    }
    carry_body(sxs, sprj, alogs, blk, k, tid, carrP, carrS);
}

// -------- k_prodD (fallback): proj -> row-major stage [56][52] + carries --------
__global__ __launch_bounds__(384, 4) void k_prodD(
        const float* __restrict__ xsd, const float* __restrict__ wcomb,
        const float* __restrict__ dtb, const float* __restrict__ alogs,
        float* __restrict__ stage, float* __restrict__ carrP, float* __restrict__ carrS) {
    __shared__ __attribute__((aligned(16))) float sxs[PERK][LCP];
    __shared__ __attribute__((aligned(16))) float sprj[56][LCP];
    __shared__ float swt[56 * PERK];
    __shared__ float sbias[PERK];
    int blk = blockIdx.x; int k = (blk >> 8) & 3;
    int tid = threadIdx.x;
    proj_body(sxs, sprj, swt, sbias, xsd, wcomb, dtb, blk, k, tid);
    float4* sg = (float4*)(stage + (size_t)blk * WST2);
    const float4* sp4 = (const float4*)&sprj[0][0];
    for (int i = tid; i < WST2 / 4; i += 384) sg[i] = sp4[i];
    carry_body(sxs, sprj, alogs, blk, k, tid, carrP, carrS);
}

// -------- k_carry: scan across 256 windows (hin may alias carrP: read-before-write) --------
__global__ void k_carry(const float* carrP, const float* carrS, float* hin) {
    int gid = blockIdx.x * blockDim.x + threadIdx.x;   // 12288
    int bk = gid / 384, ds = gid - bk * 384;
    float Hv = 0.f;
    for (int t = 0; t < TCH; ++t) {
        size_t idx = ((size_t)bk * TCH + t) * 384 + ds;
        float pv = carrP[idx], sv = carrS[idx];
        hin[idx] = Hv;
        Hv = pv * Hv + sv;
    }
}

// -------- k_base: out = x*(1+p) for UNSELECTED windows only --------
__global__ __launch_bounds__(64) void k_base(const float* __restrict__ x,
        const float* __restrict__ probs, const int* __restrict__ rank,
        float* __restrict__ out) {
    int wr = blockIdx.x % NHW; int bc = blockIdx.x / NHW;
    int b = bc / CC;
    __shared__ float buf[7 * HH];
    __shared__ float fmul[NHW];
    __shared__ int   fsel[NHW];
    int tid = threadIdx.x;
    const float* xp = x + ((size_t)bc * HH + wr * 7) * HH;
    for (int i = tid; i < 7 * HH; i += 64) buf[i] = xp[i];
    if (tid < NHW) {
        int w = wr * NHW + tid;
        fsel[tid] = (rank[b * NWIN + w] < TOPK);
        fmul[tid] = 1.0f + probs[b * NWIN + w];
    }
    __syncthreads();
    int c = bc - b * CC;
    for (int idx = tid; idx < NHW * 49; idx += 64) {
        int wc = idx / 49, r = idx - wc * 49;
        if (fsel[wc]) continue;
        int ri = r / 7, rj = r - ri * 7;
        float v = buf[ri * HH + wc * 7 + rj];
        int w = wr * NHW + wc;
        out[(((size_t)b * NWIN + w) * CC + c) * 49 + r] = v * fmul[wc];
    }
}

// -------- k_scanT: recurrence from TRANSPOSED stage; y -> xsd head --------
__global__ __launch_bounds__(384, 4) void k_scanT(
        const float* __restrict__ alogs, const float* __restrict__ dsv,
        const float* __restrict__ hin, const float* __restrict__ stage,
        float* __restrict__ xsd) {
    __shared__ __attribute__((aligned(16))) float sy[PERK][LCP];
    int blk = blockIdx.x; int k = (blk >> 8) & 3;
    int tid = threadIdx.x;
    int d = tid >> 4, s = tid & 15;
    float A = -__expf(alogs[(k * PERK + d) * DST + s]);
    float Dsr = dsv[k * PERK + d];
    size_t cidx = (size_t)blk * 384 + tid;
    float h = hin[cidx];
    const float4* pP = (const float4*)(stage + (size_t)blk * WST3) + d;   // stride 24
    const float4* pQ = (const float4*)(stage + (size_t)blk * WST3) + 600 + s; // stride 16
    // depth-2 prefetch: 2 loads per iteration (1-2 lines P, 4 lines Q per wave)
    float4 Pc = pP[0],  Qc = pQ[0];
    float4 Pn = pP[24], Qn = pQ[16];
    for (int jp = 0; jp < 25; ++jp) {
        float4 P4 = Pc, Q4 = Qc;
        Pc = Pn; Qc = Qn;
        if (jp + 2 < 25) { Pn = pP[(jp + 2) * 24]; Qn = pQ[(jp + 2) * 16]; }
        int j0 = 2 * jp;
        float aa, part;
        // step j0: P4 = (dl0, xs0, dl1, xs1); Q4 = (B0, C0, B1, C1)
        aa = __expf(P4.x * A); h = aa * h + (P4.x * P4.y) * Q4.x;
        part = h * Q4.y;
        ROR_ADD(part, 0x121); ROR_ADD(part, 0x122); ROR_ADD(part, 0x124); ROR_ADD(part, 0x128);
        if (s == 0) sy[d][j0] = part + P4.y * Dsr;
        // step j0+1 (jp=24 second slot is zero-padded: aa=1, du=0 -> no-op)
        aa = __expf(P4.z * A); h = aa * h + (P4.z * P4.w) * Q4.z;
        part = h * Q4.w;
        ROR_ADD(part, 0x121); ROR_ADD(part, 0x122); ROR_ADD(part, 0x124); ROR_ADD(part, 0x128);
        if (s == 0 && j0 + 1 < 49) sy[d][j0 + 1] = part + P4.w * Dsr;
    }
    __syncthreads();
    float* yout = xsd + (size_t)blk * XROW;   // y[j][d], 1176 floats, contiguous
    for (int idx = tid; idx < PERK * 49; idx += 384) {
        int j = idx / PERK, d2 = idx - j * PERK;
        yout[idx] = sy[d2][j];
    }
}

// -------- k_scan2 (fallback): recurrence from row-major stage; y -> stage head --------
__global__ __launch_bounds__(384, 4) void k_scan2(
        const float* __restrict__ alogs, const float* __restrict__ dsv,
        const float* __restrict__ hin, const float* __restrict__ xsd,
        float* __restrict__ stage) {
    __shared__ __attribute__((aligned(16))) float sy[PERK][LCP];
    int blk = blockIdx.x; int k = (blk >> 8) & 3;
    int tid = threadIdx.x;
    int d = tid >> 4, s = tid & 15;
    float A = -__expf(alogs[(k * PERK + d) * DST + s]);
    float Dsr = dsv[k * PERK + d];
    size_t cidx = (size_t)blk * 384 + tid;
    float h = hin[cidx];
    const float* sg = stage + (size_t)blk * WST2;
    const float* pdl = sg + d * LCP;
    const float* pB  = sg + (24 + s) * LCP;
    const float* pC  = sg + (40 + s) * LCP;
    const float* pxs = xsd + (size_t)blk * XROW + d * LCP;
    float4 dlC = *(const float4*)(pdl);     float4 xsC = *(const float4*)(pxs);
    float4 BC_ = *(const float4*)(pB);      float4 CC_ = *(const float4*)(pC);
    float4 dlN = *(const float4*)(pdl + 4); float4 xsN = *(const float4*)(pxs + 4);
    float4 BN_ = *(const float4*)(pB + 4);  float4 CN_ = *(const float4*)(pC + 4);
    for (int g = 0; g < NG; ++g) {
        float4 dl4 = dlC, xs4 = xsC, B4 = BC_, C4 = CC_;
        dlC = dlN; xsC = xsN; BC_ = BN_; CC_ = CN_;
        if (g + 2 < NG) {
            int jn = (g + 2) * 4;
            dlN = *(const float4*)(pdl + jn); xsN = *(const float4*)(pxs + jn);
            BN_ = *(const float4*)(pB + jn);  CN_ = *(const float4*)(pC + jn);
        }
        int j = g * 4;
        float aa, part;
        aa = __expf(dl4.x * A); h = aa * h + (dl4.x * xs4.x) * B4.x;
        part = h * C4.x;
        ROR_ADD(part, 0x121); ROR_ADD(part, 0x122); ROR_ADD(part, 0x124); ROR_ADD(part, 0x128);
        if (s == 0) sy[d][j] = part + xs4.x * Dsr;
        aa = __expf(dl4.y * A); h = aa * h + (dl4.y * xs4.y) * B4.y;
        part = h * C4.y;
        ROR_ADD(part, 0x121); ROR_ADD(part, 0x122); ROR_ADD(part, 0x124); ROR_ADD(part, 0x128);
        if (s == 0 && j + 1 < 49) sy[d][j + 1] = part + xs4.y * Dsr;
        aa = __expf(dl4.z * A); h = aa * h + (dl4.z * xs4.z) * B4.z;
        part = h * C4.z;
        ROR_ADD(part, 0x121); ROR_ADD(part, 0x122); ROR_ADD(part, 0x124); ROR_ADD(part, 0x128);
        if (s == 0 && j + 2 < 49) sy[d][j + 2] = part + xs4.z * Dsr;
        aa = __expf(dl4.w * A); h = aa * h + (dl4.w * xs4.w) * B4.w;
        part = h * C4.w;
        ROR_ADD(part, 0x121); ROR_ADD(part, 0x122); ROR_ADD(part, 0x124); ROR_ADD(part, 0x128);
        if (s == 0 && j + 3 < 49) sy[d][j + 3] = part + xs4.w * Dsr;
    }
    __syncthreads();
    float* yout = stage + (size_t)blk * WST2;
    for (int idx = tid; idx < PERK * 49; idx += 384) {
        int j = idx / PERK, d2 = idx - j * PERK;
        yout[idx] = sy[d2][j];
    }
}

// -------- k_yadd: selected windows written DIRECTLY: out = x + p*y (no RMW) --------
__global__ __launch_bounds__(256) void k_yadd(const float* __restrict__ ysrc,
        const float* __restrict__ x, const int* __restrict__ sel,
        const float* __restrict__ rw, float* __restrict__ out, int ystride) {
    __shared__ float ytile[CC * 49];
    int qo = blockIdx.x & 255; int b = blockIdx.x >> 8;
    int wsel = sel[b * TOPK + qo];
    float p = rw[b * TOPK + qo];
    for (int idx = threadIdx.x; idx < CC * 49; idx += 256) {
        int k = idx / 1176; int r1 = idx - k * 1176;
        int u = r1 / 168;   int r2 = r1 - u * 168;
        int wj = r2 / 24;   int d = r2 - wj * 24;
        int rest = qo * 7 + u;
        int b2 = rest & 15; int aw = rest >> 4;
        int wi = aw % 7;    int a = aw / 7;
        int q   = (k & 1) ? (b2 * 16 + a) : (a * 16 + b2);
        int pix = (k & 1) ? (wj * 7 + wi) : (wi * 7 + wj);
        int uu = q * 49 + pix;
        int l = (k >= 2) ? (LL - 1 - uu) : uu;
        int bk = b * 4 + k;
        int t2 = l / 49, jj = l - t2 * 49;
        ytile[(k * PERK + d) * 49 + u * 7 + wj] =
            p * ysrc[((size_t)(bk * 256 + t2)) * ystride + jj * PERK + d];
    }
    __syncthreads();
    float* ob = out + ((size_t)(b * NWIN + wsel) * CC) * 49;
    int gi0 = (wsel >> 5) * 7, gj0 = (wsel & 31) * 7;
    for (int e = threadIdx.x; e < CC * 49; e += 256) {
        int C = e / 49, cell = e - C * 49;
        int u = cell / 7, wj = cell - u * 7;
        float xv = x[(((size_t)b * CC + C) * HH + gi0 + u) * HH + gj0 + wj];
        ob[e] = xv + ytile[e];
    }
}

extern "C" void kernel_launch(void* const* d_in, const int* in_sizes, int n_in,
                              void* d_out, int out_size, void* d_ws, size_t ws_size,
                              hipStream_t stream) {
    const float* x   = (const float*)d_in[0];
    const float* w1  = (const float*)d_in[1];
    const float* b1  = (const float*)d_in[2];
    const float* w2  = (const float*)d_in[3];
    const float* b2  = (const float*)d_in[4];
    const float* xpw = (const float*)d_in[5];
    const float* dtw = (const float*)d_in[6];
    const float* dtb = (const float*)d_in[7];
    const float* alg = (const float*)d_in[8];
    const float* dsv = (const float*)d_in[9];
    float* out = (float*)d_out;
    float* ws  = (float*)d_ws;

    float* pooled = ws + OFF_POOL;
    float* logits = ws + OFF_LOG;
    float* probs  = ws + OFF_PROB;
    float* rwv    = ws + OFF_RW;
    int*   rank   = (int*)(ws + OFF_RANK);
    int*   sel    = (int*)(ws + OFF_SEL);
    float* wcomb  = ws + OFF_WEFF;
    float* cP  = ws + OFF_CP;       // also hin after k_carry
    float* cS  = ws + OFF_CS;
    float* xsd = ws + OFF_XSD;      // xs dense; y reuses head in transposed path
    float* stage = ws + OFF_STG;

    k_pool  <<<BBATCH * CC, 256, 0, stream>>>(x, pooled);
    k_router<<<BBATCH * 16, 64, 0, stream>>>(pooled, w1, b1, w2, b2, logits);
    k_rankF <<<BBATCH * 16, 64, 0, stream>>>(logits, probs, rwv, rank, sel);
    k_weff  <<<(4 * 56 * PERK + 255) / 256, 256, 0, stream>>>(xpw, dtw, wcomb);
    k_gather<<<2048, 256, 0, stream>>>(x, sel, xsd);

    if (ws_size >= NEED_T) {
        k_prodT<<<NBK * TCH, 384, 0, stream>>>(xsd, wcomb, dtb, alg, stage, cP, cS);
        k_carry<<<48, 256, 0, stream>>>(cP, cS, cP);
        k_base <<<BBATCH * CC * NHW, 64, 0, stream>>>(x, probs, rank, out);
        k_scanT<<<NBK * TCH, 384, 0, stream>>>(alg, dsv, cP, stage, xsd);
        k_yadd <<<BBATCH * TOPK, 256, 0, stream>>>(xsd, x, sel, rwv, out, XROW);
    } else {
        k_prodD<<<NBK * TCH, 384, 0, stream>>>(xsd, wcomb, dtb, alg, stage, cP, cS);
        k_carry<<<48, 256, 0, stream>>>(cP, cS, cP);
        k_base <<<BBATCH * CC * NHW, 64, 0, stream>>>(x, probs, rank, out);
        k_scan2<<<NBK * TCH, 384, 0, stream>>>(alg, dsv, cP, xsd, stage);
        k_yadd <<<BBATCH * TOPK, 256, 0, stream>>>(stage, x, sel, rwv, out, WST2);
    }
}